// Round 1
// baseline (7369.673 us; speedup 1.0000x reference)
//
#include <hip/hip_runtime.h>
#include <hip/hip_bf16.h>
#include <math.h>

#define NN 50000
#define EE 800000
#define ET 850000   // EE + NN self loops
#define DIN 128
#define HEADS 8
#define DH 16
#define DOUT 16
#define NEG 0.2f

// ---------- helpers ----------
__device__ __forceinline__ unsigned fenc(float f) {
    unsigned u = __float_as_uint(f);
    return (u & 0x80000000u) ? ~u : (u | 0x80000000u);
}
__device__ __forceinline__ float fdec(unsigned u) {
    u = (u & 0x80000000u) ? (u & 0x7fffffffu) : ~u;
    return __uint_as_float(u);
}
__device__ __forceinline__ void edge_sd(const int* __restrict__ ei, int e, int& s, int& d) {
    if (e < EE) { s = ei[e]; d = ei[EE + e]; }
    else        { s = e - EE; d = s; }
}

// ---------- layer-1 GEMMs: xl1 = x@Wl1, xr1 = x@Wr1 ----------
__global__ void gemm1(const float* __restrict__ x, const float* __restrict__ Wl,
                      const float* __restrict__ Wr,
                      float* __restrict__ xl, float* __restrict__ xr) {
    int n = blockIdx.x;
    __shared__ float xs[DIN];
    int t = threadIdx.x;
    if (t < DIN) xs[t] = x[(size_t)n * DIN + t];
    __syncthreads();
    int j = t & (DIN - 1);
    const float* __restrict__ W = (t < DIN) ? Wl : Wr;
    float acc = 0.f;
#pragma unroll 8
    for (int i = 0; i < DIN; ++i) acc += xs[i] * W[i * DIN + j];
    if (t < DIN) xl[(size_t)n * DIN + j] = acc;
    else         xr[(size_t)n * DIN + j] = acc;
}

// ---------- layer-1 edge logits + segment max (thread per edge*head) ----------
__global__ void edge_logits1(const int* __restrict__ ei,
                             const float* __restrict__ xl, const float* __restrict__ xr,
                             const float* __restrict__ att,
                             float* __restrict__ logits, unsigned* __restrict__ nmax) {
    int idx = blockIdx.x * blockDim.x + threadIdx.x;
    if (idx >= ET * HEADS) return;
    int e = idx >> 3, h = idx & 7;
    int s, d; edge_sd(ei, e, s, d);
    const float4* A = (const float4*)(xl + (size_t)s * DIN + h * DH);
    const float4* B = (const float4*)(xr + (size_t)d * DIN + h * DH);
    const float4* T = (const float4*)(att + h * DH);
    float acc = 0.f;
#pragma unroll
    for (int k = 0; k < 4; ++k) {
        float4 a = A[k], b = B[k], w = T[k];
        float v;
        v = a.x + b.x; v = v > 0.f ? v : NEG * v; acc += w.x * v;
        v = a.y + b.y; v = v > 0.f ? v : NEG * v; acc += w.y * v;
        v = a.z + b.z; v = v > 0.f ? v : NEG * v; acc += w.z * v;
        v = a.w + b.w; v = v > 0.f ? v : NEG * v; acc += w.w * v;
    }
    logits[idx] = acc;
    atomicMax(&nmax[(size_t)d * HEADS + h], fenc(acc));
}

// ---------- layer-1 exp + segment sum ----------
__global__ void edge_exp1(const int* __restrict__ ei,
                          float* __restrict__ logits,  // in: logits, out: exp(a)
                          const unsigned* __restrict__ nmax,
                          float* __restrict__ denom) {
    int idx = blockIdx.x * blockDim.x + threadIdx.x;
    if (idx >= ET * HEADS) return;
    int e = idx >> 3, h = idx & 7;
    int s, d; edge_sd(ei, e, s, d);
    float a = expf(logits[idx] - fdec(nmax[(size_t)d * HEADS + h]));
    logits[idx] = a;
    atomicAdd(&denom[(size_t)d * HEADS + h], a);
}

// ---------- layer-1 scatter: hout[dst] += xl[src]*alpha ----------
__global__ void edge_scatter1(const int* __restrict__ ei,
                              const float* __restrict__ aexp,
                              const float* __restrict__ denom,
                              const float* __restrict__ xl,
                              float* __restrict__ hout) {
    int idx = blockIdx.x * blockDim.x + threadIdx.x;
    if (idx >= ET * HEADS) return;
    int e = idx >> 3, h = idx & 7;
    int s, d; edge_sd(ei, e, s, d);
    float alpha = aexp[idx] / denom[(size_t)d * HEADS + h];
    const float* __restrict__ srow = xl + (size_t)s * DIN + h * DH;
    float* __restrict__ drow = hout + (size_t)d * DIN + h * DH;
#pragma unroll
    for (int k = 0; k < DH; ++k) atomicAdd(&drow[k], srow[k] * alpha);
}

// ---------- elu(h + bias1) in place ----------
__global__ void elu_bias(float* __restrict__ h, const float* __restrict__ bias) {
    int i = blockIdx.x * blockDim.x + threadIdx.x;
    if (i >= NN * DIN) return;
    float v = h[i] + bias[i & (DIN - 1)];
    h[i] = v > 0.f ? v : expm1f(v);
}

// ---------- layer-2 GEMMs: xl2 = h@Wl2, xr2 = h@Wr2 (thread per (n, j<32)) ----------
__global__ void gemm2(const float* __restrict__ h, const float* __restrict__ Wl,
                      const float* __restrict__ Wr,
                      float* __restrict__ xl, float* __restrict__ xr) {
    int idx = blockIdx.x * blockDim.x + threadIdx.x;
    if (idx >= NN * 32) return;
    int n = idx >> 5, j = idx & 31;
    const float* __restrict__ W = (j < DOUT) ? Wl : Wr;
    int jj = j & (DOUT - 1);
    const float* __restrict__ hr = h + (size_t)n * DIN;
    float acc = 0.f;
#pragma unroll 8
    for (int i = 0; i < DIN; ++i) acc += hr[i] * W[i * DOUT + jj];
    if (j < DOUT) xl[(size_t)n * DOUT + jj] = acc;
    else          xr[(size_t)n * DOUT + jj] = acc;
}

// ---------- layer-2 edge logits + max (thread per edge) ----------
__global__ void edge_logits2(const int* __restrict__ ei,
                             const float* __restrict__ xl, const float* __restrict__ xr,
                             const float* __restrict__ att,
                             float* __restrict__ logits, unsigned* __restrict__ nmax) {
    int e = blockIdx.x * blockDim.x + threadIdx.x;
    if (e >= ET) return;
    int s, d; edge_sd(ei, e, s, d);
    const float4* A = (const float4*)(xl + (size_t)s * DOUT);
    const float4* B = (const float4*)(xr + (size_t)d * DOUT);
    const float4* T = (const float4*)att;
    float acc = 0.f;
#pragma unroll
    for (int k = 0; k < 4; ++k) {
        float4 a = A[k], b = B[k], w = T[k];
        float v;
        v = a.x + b.x; v = v > 0.f ? v : NEG * v; acc += w.x * v;
        v = a.y + b.y; v = v > 0.f ? v : NEG * v; acc += w.y * v;
        v = a.z + b.z; v = v > 0.f ? v : NEG * v; acc += w.z * v;
        v = a.w + b.w; v = v > 0.f ? v : NEG * v; acc += w.w * v;
    }
    logits[e] = acc;
    atomicMax(&nmax[d], fenc(acc));
}

__global__ void edge_exp2(const int* __restrict__ ei,
                          float* __restrict__ logits,
                          const unsigned* __restrict__ nmax,
                          float* __restrict__ denom) {
    int e = blockIdx.x * blockDim.x + threadIdx.x;
    if (e >= ET) return;
    int s, d; edge_sd(ei, e, s, d);
    float a = expf(logits[e] - fdec(nmax[d]));
    logits[e] = a;
    atomicAdd(&denom[d], a);
}

__global__ void edge_scatter2(const int* __restrict__ ei,
                              const float* __restrict__ aexp,
                              const float* __restrict__ denom,
                              const float* __restrict__ xl,
                              float* __restrict__ out2) {
    int e = blockIdx.x * blockDim.x + threadIdx.x;
    if (e >= ET) return;
    int s, d; edge_sd(ei, e, s, d);
    float alpha = aexp[e] / denom[d];
    const float* __restrict__ srow = xl + (size_t)s * DOUT;
    float* __restrict__ drow = out2 + (size_t)d * DOUT;
#pragma unroll
    for (int k = 0; k < DOUT; ++k) atomicAdd(&drow[k], srow[k] * alpha);
}

// ---------- final: +bias2, write h and log_softmax(h) ----------
__global__ void finalize(const float* __restrict__ h2, const float* __restrict__ bias,
                         float* __restrict__ out) {
    int n = blockIdx.x * blockDim.x + threadIdx.x;
    if (n >= NN) return;
    float v[DOUT];
    float m = -INFINITY;
#pragma unroll
    for (int c = 0; c < DOUT; ++c) {
        v[c] = h2[(size_t)n * DOUT + c] + bias[c];
        m = fmaxf(m, v[c]);
    }
    float ssum = 0.f;
#pragma unroll
    for (int c = 0; c < DOUT; ++c) ssum += expf(v[c] - m);
    float lse = m + logf(ssum);
#pragma unroll
    for (int c = 0; c < DOUT; ++c) {
        out[(size_t)n * DOUT + c] = v[c];
        out[(size_t)NN * DOUT + (size_t)n * DOUT + c] = v[c] - lse;
    }
}

extern "C" void kernel_launch(void* const* d_in, const int* in_sizes, int n_in,
                              void* d_out, int out_size, void* d_ws, size_t ws_size,
                              hipStream_t stream) {
    const float* x     = (const float*)d_in[0];
    const int*   ei    = (const int*)d_in[1];
    const float* Wl1   = (const float*)d_in[2];
    const float* Wr1   = (const float*)d_in[3];
    const float* att1  = (const float*)d_in[4];
    const float* bias1 = (const float*)d_in[5];
    const float* Wl2   = (const float*)d_in[6];
    const float* Wr2   = (const float*)d_in[7];
    const float* att2  = (const float*)d_in[8];
    const float* bias2 = (const float*)d_in[9];
    float* out = (float*)d_out;

    // ---- workspace layout (floats) ----
    float* xl1     = (float*)d_ws;            // NN*128
    float* xr1     = xl1 + (size_t)NN * DIN;  // NN*128
    float* logits1 = xr1 + (size_t)NN * DIN;  // ET*8
    float* xl2     = logits1 + (size_t)ET * HEADS; // NN*16
    float* xr2     = xl2 + (size_t)NN * DOUT;      // NN*16
    float* logits2 = xr2 + (size_t)NN * DOUT;      // ET
    // zero-init region (contiguous):
    float* zbase   = logits2 + (size_t)ET;
    unsigned* nmax1 = (unsigned*)zbase;                  // NN*8
    float* denom1  = zbase + (size_t)NN * HEADS;         // NN*8
    float* hout    = denom1 + (size_t)NN * HEADS;        // NN*128
    unsigned* nmax2 = (unsigned*)(hout + (size_t)NN * DIN); // NN
    float* denom2  = (float*)nmax2 + NN;                 // NN
    float* out2    = denom2 + NN;                        // NN*16
    size_t zcount  = (size_t)NN * (HEADS + HEADS + DIN + 1 + 1 + DOUT);

    hipMemsetAsync(zbase, 0, zcount * sizeof(float), stream);

    const int B = 256;
    gemm1<<<NN, B, 0, stream>>>(x, Wl1, Wr1, xl1, xr1);

    int gEH = (ET * HEADS + B - 1) / B;
    edge_logits1 <<<gEH, B, 0, stream>>>(ei, xl1, xr1, att1, logits1, nmax1);
    edge_exp1    <<<gEH, B, 0, stream>>>(ei, logits1, nmax1, denom1);
    edge_scatter1<<<gEH, B, 0, stream>>>(ei, logits1, denom1, xl1, hout);

    elu_bias<<<(NN * DIN + B - 1) / B, B, 0, stream>>>(hout, bias1);

    gemm2<<<(NN * 32 + B - 1) / B, B, 0, stream>>>(hout, Wl2, Wr2, xl2, xr2);

    int gE = (ET + B - 1) / B;
    edge_logits2 <<<gE, B, 0, stream>>>(ei, xl2, xr2, att2, logits2, nmax2);
    edge_exp2    <<<gE, B, 0, stream>>>(ei, logits2, nmax2, denom2);
    edge_scatter2<<<gE, B, 0, stream>>>(ei, logits2, denom2, xl2, out2);

    finalize<<<(NN + B - 1) / B, B, 0, stream>>>(out2, bias2, out);
}

// Round 2
// 701.684 us; speedup vs baseline: 10.5028x; 10.5028x over previous
//
#include <hip/hip_runtime.h>
#include <hip/hip_bf16.h>
#include <math.h>

#define NN 50000
#define EE 800000
#define ET 850000   // EE + NN self loops
#define DIN 128
#define HEADS 8
#define DH 16
#define DOUT 16
#define NEG 0.2f

__device__ __forceinline__ void edge_sd(const int* __restrict__ ei, int e, int& s, int& d) {
    if (e < EE) { s = ei[e]; d = ei[EE + e]; }
    else        { s = e - EE; d = s; }
}

// ---------- layer-1 GEMMs: xl1 = x@Wl1, xr1 = x@Wr1 ----------
__global__ void gemm1(const float* __restrict__ x, const float* __restrict__ Wl,
                      const float* __restrict__ Wr,
                      float* __restrict__ xl, float* __restrict__ xr) {
    int n = blockIdx.x;
    __shared__ float xs[DIN];
    int t = threadIdx.x;
    if (t < DIN) xs[t] = x[(size_t)n * DIN + t];
    __syncthreads();
    int j = t & (DIN - 1);
    const float* __restrict__ W = (t < DIN) ? Wl : Wr;
    float acc = 0.f;
#pragma unroll 8
    for (int i = 0; i < DIN; ++i) acc += xs[i] * W[i * DIN + j];
    if (t < DIN) xl[(size_t)n * DIN + j] = acc;
    else         xr[(size_t)n * DIN + j] = acc;
}

// ---------- CSR build ----------
__global__ void deg_count(const int* __restrict__ ei, int* __restrict__ cnt) {
    int e = blockIdx.x * blockDim.x + threadIdx.x;
    if (e >= ET) return;
    int s, d; edge_sd(ei, e, s, d);
    atomicAdd(&cnt[d], 1);
}

__global__ void scan_deg(const int* __restrict__ cnt, int* __restrict__ rowstart) {
    __shared__ int partial[1024];
    int t = threadIdx.x;
    const int C = (NN + 1023) / 1024;  // 49
    int lo = t * C, hi = lo + C; if (hi > NN) hi = NN; if (lo > NN) lo = NN;
    int s = 0;
    for (int i = lo; i < hi; ++i) s += cnt[i];
    partial[t] = s;
    __syncthreads();
    for (int off = 1; off < 1024; off <<= 1) {
        int v = (t >= off) ? partial[t - off] : 0;
        __syncthreads();
        partial[t] += v;
        __syncthreads();
    }
    int base = (t > 0) ? partial[t - 1] : 0;
    for (int i = lo; i < hi; ++i) { rowstart[i] = base; base += cnt[i]; }
    if (t == 1023) rowstart[NN] = base;   // == ET
}

__global__ void fill_csr(const int* __restrict__ ei, const int* __restrict__ rowstart,
                         int* __restrict__ cursor, int* __restrict__ esrc) {
    int e = blockIdx.x * blockDim.x + threadIdx.x;
    if (e >= ET) return;
    int s, d; edge_sd(ei, e, s, d);
    int pos = atomicAdd(&cursor[d], 1);
    esrc[rowstart[d] + pos] = s;
}

// ---------- layer-1 fused attention: logits + segment softmax -> alpha ----------
// one wave per dst node; lane l always handles head (l & 7)
__global__ __launch_bounds__(64) void l1_attn(const int* __restrict__ esrc,
                                              const int* __restrict__ rowstart,
                                              const float* __restrict__ xl,
                                              const float* __restrict__ xr,
                                              const float* __restrict__ att,
                                              float* __restrict__ alpha) {
    int d = blockIdx.x;
    int t = threadIdx.x;   // 0..63
    int rs = rowstart[d], re = rowstart[d + 1];
    int total = (re - rs) * HEADS;
    __shared__ float xrs[DIN];
    __shared__ float atts[DIN];
    xrs[t]       = xr[(size_t)d * DIN + t];
    xrs[t + 64]  = xr[(size_t)d * DIN + t + 64];
    atts[t]      = att[t];
    atts[t + 64] = att[t + 64];
    __syncthreads();
    int h = t & 7;
    const float4* xrh = (const float4*)(xrs + h * DH);
    const float4* ath = (const float4*)(atts + h * DH);
    // pass 1: logits -> alpha[], per-lane max
    float mx = -INFINITY;
    for (int i = t; i < total; i += 64) {
        int slot = rs + (i >> 3);
        int s = esrc[slot];
        const float4* A = (const float4*)(xl + (size_t)s * DIN + h * DH);
        float acc = 0.f;
#pragma unroll
        for (int k = 0; k < 4; ++k) {
            float4 a = A[k], b = xrh[k], w = ath[k];
            float v;
            v = a.x + b.x; v = v > 0.f ? v : NEG * v; acc += w.x * v;
            v = a.y + b.y; v = v > 0.f ? v : NEG * v; acc += w.y * v;
            v = a.z + b.z; v = v > 0.f ? v : NEG * v; acc += w.z * v;
            v = a.w + b.w; v = v > 0.f ? v : NEG * v; acc += w.w * v;
        }
        alpha[(size_t)slot * HEADS + h] = acc;
        mx = fmaxf(mx, acc);
    }
#pragma unroll
    for (int off = 8; off < 64; off <<= 1) mx = fmaxf(mx, __shfl_xor(mx, off));
    // pass 2: exp + per-head sum
    float sum = 0.f;
    for (int i = t; i < total; i += 64) {
        int slot = rs + (i >> 3);
        float a = expf(alpha[(size_t)slot * HEADS + h] - mx);
        alpha[(size_t)slot * HEADS + h] = a;
        sum += a;
    }
#pragma unroll
    for (int off = 8; off < 64; off <<= 1) sum += __shfl_xor(sum, off);
    float inv = 1.f / sum;
    // pass 3: normalize
    for (int i = t; i < total; i += 64) {
        int slot = rs + (i >> 3);
        alpha[(size_t)slot * HEADS + h] *= inv;
    }
}

// ---------- layer-1 gather: hout[d] = elu( sum_e alpha*xl[src] + bias ) ----------
__global__ __launch_bounds__(128) void l1_gather(const int* __restrict__ esrc,
                                                 const int* __restrict__ rowstart,
                                                 const float* __restrict__ alpha,
                                                 const float* __restrict__ xl,
                                                 const float* __restrict__ bias,
                                                 float* __restrict__ hout) {
    int d = blockIdx.x;
    int t = threadIdx.x;   // 0..127 ; channel index
    int rs = rowstart[d], re = rowstart[d + 1];
    int h = t >> 4;
    float acc = 0.f;
    for (int slot = rs; slot < re; ++slot) {
        int s = esrc[slot];
        float a = alpha[(size_t)slot * HEADS + h];
        acc += a * xl[(size_t)s * DIN + t];
    }
    float v = acc + bias[t];
    hout[(size_t)d * DIN + t] = v > 0.f ? v : expm1f(v);
}

// ---------- layer-2 GEMMs ----------
__global__ void gemm2(const float* __restrict__ h, const float* __restrict__ Wl,
                      const float* __restrict__ Wr,
                      float* __restrict__ xl, float* __restrict__ xr) {
    int idx = blockIdx.x * blockDim.x + threadIdx.x;
    if (idx >= NN * 32) return;
    int n = idx >> 5, j = idx & 31;
    const float* __restrict__ W = (j < DOUT) ? Wl : Wr;
    int jj = j & (DOUT - 1);
    const float* __restrict__ hr = h + (size_t)n * DIN;
    float acc = 0.f;
#pragma unroll 8
    for (int i = 0; i < DIN; ++i) acc += hr[i] * W[i * DOUT + jj];
    if (j < DOUT) xl[(size_t)n * DOUT + jj] = acc;
    else          xr[(size_t)n * DOUT + jj] = acc;
}

// ---------- layer-2 fused attention (1 head) ----------
__global__ __launch_bounds__(64) void l2_attn(const int* __restrict__ esrc,
                                              const int* __restrict__ rowstart,
                                              const float* __restrict__ xl,
                                              const float* __restrict__ xr,
                                              const float* __restrict__ att,
                                              float* __restrict__ alpha) {
    int d = blockIdx.x;
    int t = threadIdx.x;
    int rs = rowstart[d], re = rowstart[d + 1];
    __shared__ float xrs[DOUT];
    __shared__ float atts[DOUT];
    if (t < DOUT) { xrs[t] = xr[(size_t)d * DOUT + t]; atts[t] = att[t]; }
    __syncthreads();
    const float4* xrh = (const float4*)xrs;
    const float4* ath = (const float4*)atts;
    float mx = -INFINITY;
    for (int slot = rs + t; slot < re; slot += 64) {
        int s = esrc[slot];
        const float4* A = (const float4*)(xl + (size_t)s * DOUT);
        float acc = 0.f;
#pragma unroll
        for (int k = 0; k < 4; ++k) {
            float4 a = A[k], b = xrh[k], w = ath[k];
            float v;
            v = a.x + b.x; v = v > 0.f ? v : NEG * v; acc += w.x * v;
            v = a.y + b.y; v = v > 0.f ? v : NEG * v; acc += w.y * v;
            v = a.z + b.z; v = v > 0.f ? v : NEG * v; acc += w.z * v;
            v = a.w + b.w; v = v > 0.f ? v : NEG * v; acc += w.w * v;
        }
        alpha[slot] = acc;
        mx = fmaxf(mx, acc);
    }
#pragma unroll
    for (int off = 1; off < 64; off <<= 1) mx = fmaxf(mx, __shfl_xor(mx, off));
    float sum = 0.f;
    for (int slot = rs + t; slot < re; slot += 64) {
        float a = expf(alpha[slot] - mx);
        alpha[slot] = a;
        sum += a;
    }
#pragma unroll
    for (int off = 1; off < 64; off <<= 1) sum += __shfl_xor(sum, off);
    float inv = 1.f / sum;
    for (int slot = rs + t; slot < re; slot += 64) alpha[slot] *= inv;
}

// ---------- layer-2 gather + bias + log_softmax (16 dst per block) ----------
__global__ __launch_bounds__(256) void l2_gather_final(const int* __restrict__ esrc,
                                                       const int* __restrict__ rowstart,
                                                       const float* __restrict__ alpha,
                                                       const float* __restrict__ xl,
                                                       const float* __restrict__ bias,
                                                       float* __restrict__ out) {
    int t = threadIdx.x;
    int c = t & 15;
    int d = blockIdx.x * 16 + (t >> 4);
    if (d >= NN) return;
    int rs = rowstart[d], re = rowstart[d + 1];
    float acc = 0.f;
    for (int slot = rs; slot < re; ++slot) {
        acc += alpha[slot] * xl[(size_t)esrc[slot] * DOUT + c];
    }
    float v = acc + bias[c];
    // 16-lane group reductions (lanes differ only in low 4 bits)
    float m = v;
#pragma unroll
    for (int off = 1; off < 16; off <<= 1) m = fmaxf(m, __shfl_xor(m, off));
    float s = expf(v - m);
#pragma unroll
    for (int off = 1; off < 16; off <<= 1) s += __shfl_xor(s, off);
    float lse = m + logf(s);
    out[(size_t)d * DOUT + c] = v;
    out[(size_t)NN * DOUT + (size_t)d * DOUT + c] = v - lse;
}

extern "C" void kernel_launch(void* const* d_in, const int* in_sizes, int n_in,
                              void* d_out, int out_size, void* d_ws, size_t ws_size,
                              hipStream_t stream) {
    const float* x     = (const float*)d_in[0];
    const int*   ei    = (const int*)d_in[1];
    const float* Wl1   = (const float*)d_in[2];
    const float* Wr1   = (const float*)d_in[3];
    const float* att1  = (const float*)d_in[4];
    const float* bias1 = (const float*)d_in[5];
    const float* Wl2   = (const float*)d_in[6];
    const float* Wr2   = (const float*)d_in[7];
    const float* att2  = (const float*)d_in[8];
    const float* bias2 = (const float*)d_in[9];
    float* out = (float*)d_out;

    // ---- workspace layout (floats; all 16B-aligned except trailing int arrays) ----
    float* xl1    = (float*)d_ws;                    // NN*128
    float* xr1    = xl1 + (size_t)NN * DIN;          // NN*128
    float* hout   = xr1 + (size_t)NN * DIN;          // NN*128
    float* alpha1 = hout + (size_t)NN * DIN;         // ET*8
    float* xl2    = alpha1 + (size_t)ET * HEADS;     // NN*16
    float* xr2    = xl2 + (size_t)NN * DOUT;         // NN*16
    float* alpha2 = xr2 + (size_t)NN * DOUT;         // ET
    int*   esrc   = (int*)(alpha2 + (size_t)ET);     // ET
    int*   rowstart = esrc + (size_t)ET;             // NN+1
    // zero-init region:
    int*   cnt    = rowstart + NN + 1;               // NN
    int*   cursor = cnt + NN;                        // NN

    hipMemsetAsync(cnt, 0, (size_t)2 * NN * sizeof(int), stream);

    const int B = 256;
    gemm1<<<NN, B, 0, stream>>>(x, Wl1, Wr1, xl1, xr1);

    int gE = (ET + B - 1) / B;
    deg_count<<<gE, B, 0, stream>>>(ei, cnt);
    scan_deg<<<1, 1024, 0, stream>>>(cnt, rowstart);
    fill_csr<<<gE, B, 0, stream>>>(ei, rowstart, cursor, esrc);

    l1_attn  <<<NN, 64, 0, stream>>>(esrc, rowstart, xl1, xr1, att1, alpha1);
    l1_gather<<<NN, 128, 0, stream>>>(esrc, rowstart, alpha1, xl1, bias1, hout);

    gemm2<<<(NN * 32 + B - 1) / B, B, 0, stream>>>(hout, Wl2, Wr2, xl2, xr2);

    l2_attn<<<NN, 64, 0, stream>>>(esrc, rowstart, xl2, xr2, att2, alpha2);
    l2_gather_final<<<(NN + 15) / 16, 256, 0, stream>>>(esrc, rowstart, alpha2, xl2, bias2, out);
}

// Round 3
// 506.585 us; speedup vs baseline: 14.5477x; 1.3851x over previous
//
#include <hip/hip_runtime.h>
#include <hip/hip_bf16.h>
#include <math.h>

#define NN 50000
#define EE 800000
#define ET 850000   // EE + NN self loops
#define DIN 128
#define HEADS 8
#define DH 16
#define DOUT 16
#define NEG 0.2f
#define GM 32       // nodes per GEMM block

__device__ __forceinline__ void edge_sd(const int* __restrict__ ei, int e, int& s, int& d) {
    if (e < EE) { s = ei[e]; d = ei[EE + e]; }
    else        { s = e - EE; d = s; }
}

// ---------- layer-1 GEMMs: xl1 = x@Wl1, xr1 = x@Wr1 (register-tiled) ----------
// block = 256 threads, 32 nodes. thread: col-quad q (0..63 over [Wl|Wr]), node-group g.
// per K-step: 1 float4 W load + 8 broadcast LDS reads + 32 FMAs.
__global__ __launch_bounds__(256) void gemm1(const float* __restrict__ x,
                                             const float* __restrict__ Wl,
                                             const float* __restrict__ Wr,
                                             float* __restrict__ xl, float* __restrict__ xr) {
    __shared__ float xs[GM][DIN];
    int t = threadIdx.x;
    int n0 = blockIdx.x * GM;
    {   // stage 32 x-rows, coalesced float4
        int r = t >> 3, q0 = t & 7;
        int n = n0 + r;
        float4* dstq = (float4*)(xs[r]);
        if (n < NN) {
            const float4* src = (const float4*)(x + (size_t)n * DIN);
#pragma unroll
            for (int k = 0; k < 4; ++k) dstq[q0 + 8 * k] = src[q0 + 8 * k];
        } else {
#pragma unroll
            for (int k = 0; k < 4; ++k) dstq[q0 + 8 * k] = make_float4(0.f, 0.f, 0.f, 0.f);
        }
    }
    __syncthreads();
    int q = t & 63;        // 64 col-quads: 0..31 -> Wl, 32..63 -> Wr
    int g = t >> 6;        // wave-uniform node group (broadcast LDS reads)
    const float* __restrict__ W = (q < 32) ? Wl : Wr;
    int cq = q & 31;
    float4 acc[8];
#pragma unroll
    for (int j = 0; j < 8; ++j) acc[j] = make_float4(0.f, 0.f, 0.f, 0.f);
#pragma unroll 4
    for (int i = 0; i < DIN; ++i) {
        float4 w = ((const float4*)(W + (size_t)i * 128))[cq];
#pragma unroll
        for (int j = 0; j < 8; ++j) {
            float xv = xs[g * 8 + j][i];
            acc[j].x += xv * w.x; acc[j].y += xv * w.y;
            acc[j].z += xv * w.z; acc[j].w += xv * w.w;
        }
    }
    float* __restrict__ dst = (q < 32) ? xl : xr;
#pragma unroll
    for (int j = 0; j < 8; ++j) {
        int n = n0 + g * 8 + j;
        if (n < NN) ((float4*)(dst + (size_t)n * DIN))[cq] = acc[j];
    }
}

// ---------- CSR build ----------
__global__ void deg_count(const int* __restrict__ ei, int* __restrict__ cnt) {
    int e = blockIdx.x * blockDim.x + threadIdx.x;
    if (e >= ET) return;
    int s, d; edge_sd(ei, e, s, d);
    atomicAdd(&cnt[d], 1);
}

__global__ void scan_deg(const int* __restrict__ cnt, int* __restrict__ rowstart) {
    __shared__ int partial[1024];
    int t = threadIdx.x;
    const int C = (NN + 1023) / 1024;  // 49
    int lo = t * C, hi = lo + C; if (hi > NN) hi = NN; if (lo > NN) lo = NN;
    int s = 0;
    for (int i = lo; i < hi; ++i) s += cnt[i];
    partial[t] = s;
    __syncthreads();
    for (int off = 1; off < 1024; off <<= 1) {
        int v = (t >= off) ? partial[t - off] : 0;
        __syncthreads();
        partial[t] += v;
        __syncthreads();
    }
    int base = (t > 0) ? partial[t - 1] : 0;
    for (int i = lo; i < hi; ++i) { rowstart[i] = base; base += cnt[i]; }
    if (t == 1023) rowstart[NN] = base;   // == ET
}

__global__ void fill_csr(const int* __restrict__ ei, const int* __restrict__ rowstart,
                         int* __restrict__ cursor, int* __restrict__ esrc) {
    int e = blockIdx.x * blockDim.x + threadIdx.x;
    if (e >= ET) return;
    int s, d; edge_sd(ei, e, s, d);
    int pos = atomicAdd(&cursor[d], 1);
    esrc[rowstart[d] + pos] = s;
}

// ---------- layer-1 fused: logits + online segment softmax + gather + bias + ELU ----------
// one block (128 threads) per dst; thread t = channel c; head h = c>>4.
// single pass over edges: each 512B xl row read feeds both logit and accumulation.
__global__ __launch_bounds__(128) void l1_fused(const int* __restrict__ esrc,
                                                const int* __restrict__ rowstart,
                                                const float* __restrict__ xl,
                                                const float* __restrict__ xr,
                                                const float* __restrict__ att,
                                                const float* __restrict__ bias,
                                                float* __restrict__ hout) {
    int d = blockIdx.x;
    int c = threadIdx.x;
    int rs = rowstart[d], re = rowstart[d + 1];
    float xrc  = xr[(size_t)d * DIN + c];
    float attc = att[c];
    float m = -INFINITY, l = 0.f, acc = 0.f;
    int s0 = esrc[rs];
    float xv = xl[(size_t)s0 * DIN + c];
    for (int slot = rs; slot < re; ++slot) {
        float cur = xv;
        if (slot + 1 < re) {                 // prefetch next row (hides gather latency)
            int sn = esrc[slot + 1];
            xv = xl[(size_t)sn * DIN + c];
        }
        float v = cur + xrc; v = v > 0.f ? v : NEG * v;
        float w = attc * v;
        // per-head (16-lane) reduce -> logit, replicated in all 16 lanes
        w += __shfl_xor(w, 1); w += __shfl_xor(w, 2);
        w += __shfl_xor(w, 4); w += __shfl_xor(w, 8);
        float mn = fmaxf(m, w);
        float sc = expf(m - mn);             // m=-inf first iter -> 0
        float p  = expf(w - mn);
        acc = acc * sc + p * cur;
        l   = l * sc + p;
        m = mn;
    }
    float v = acc / l + bias[c];
    hout[(size_t)d * DIN + c] = v > 0.f ? v : expm1f(v);
}

// ---------- layer-2 GEMMs (register-tiled, W in L1) ----------
__global__ __launch_bounds__(256) void gemm2(const float* __restrict__ h,
                                             const float* __restrict__ Wl,
                                             const float* __restrict__ Wr,
                                             float* __restrict__ xl, float* __restrict__ xr) {
    __shared__ float xs[GM][DIN + 4];   // pad to 132: conflict-free per-lane reads, 16B-aligned rows
    int t = threadIdx.x;
    int n0 = blockIdx.x * GM;
    {
        int r = t >> 3, q0 = t & 7;
        int n = n0 + r;
        float4* dstq = (float4*)(xs[r]);
        if (n < NN) {
            const float4* src = (const float4*)(h + (size_t)n * DIN);
#pragma unroll
            for (int k = 0; k < 4; ++k) dstq[q0 + 8 * k] = src[q0 + 8 * k];
        } else {
#pragma unroll
            for (int k = 0; k < 4; ++k) dstq[q0 + 8 * k] = make_float4(0.f, 0.f, 0.f, 0.f);
        }
    }
    __syncthreads();
    int q = t & 7;          // 8 col-quads: 0..3 -> Wl2, 4..7 -> Wr2
    int g = t >> 3;         // node within tile
    const float* __restrict__ W = (q < 4) ? Wl : Wr;
    int cq = q & 3;
    float4 acc = make_float4(0.f, 0.f, 0.f, 0.f);
#pragma unroll 8
    for (int i = 0; i < DIN; ++i) {
        float4 w = ((const float4*)(W + (size_t)i * DOUT))[cq];
        float xv = xs[g][i];
        acc.x += xv * w.x; acc.y += xv * w.y; acc.z += xv * w.z; acc.w += xv * w.w;
    }
    int n = n0 + g;
    if (n < NN) {
        float* __restrict__ dst = (q < 4) ? xl : xr;
        ((float4*)(dst + (size_t)n * DOUT))[cq] = acc;
    }
}

// ---------- layer-2 fused: online softmax + gather + bias + log_softmax ----------
// 16 lanes per dst, 16 dst per 256-thread block.
__global__ __launch_bounds__(256) void l2_fused(const int* __restrict__ esrc,
                                                const int* __restrict__ rowstart,
                                                const float* __restrict__ xl,
                                                const float* __restrict__ xr,
                                                const float* __restrict__ att,
                                                const float* __restrict__ bias,
                                                float* __restrict__ out) {
    int t = threadIdx.x;
    int c = t & 15;
    int d = blockIdx.x * 16 + (t >> 4);
    if (d >= NN) return;
    int rs = rowstart[d], re = rowstart[d + 1];
    float xrc  = xr[(size_t)d * DOUT + c];
    float attc = att[c];
    float m = -INFINITY, l = 0.f, acc = 0.f;
    int s0 = esrc[rs];
    float xv = xl[(size_t)s0 * DOUT + c];
    for (int slot = rs; slot < re; ++slot) {
        float cur = xv;
        if (slot + 1 < re) {
            int sn = esrc[slot + 1];
            xv = xl[(size_t)sn * DOUT + c];
        }
        float v = cur + xrc; v = v > 0.f ? v : NEG * v;
        float w = attc * v;
        w += __shfl_xor(w, 1); w += __shfl_xor(w, 2);
        w += __shfl_xor(w, 4); w += __shfl_xor(w, 8);
        float mn = fmaxf(m, w);
        float sc = expf(m - mn);
        float p  = expf(w - mn);
        acc = acc * sc + p * cur;
        l   = l * sc + p;
        m = mn;
    }
    float v = acc / l + bias[c];
    // log_softmax over the 16 channels (16-lane group reductions)
    float m2 = v;
#pragma unroll
    for (int off = 1; off < 16; off <<= 1) m2 = fmaxf(m2, __shfl_xor(m2, off));
    float e2 = expf(v - m2);
#pragma unroll
    for (int off = 1; off < 16; off <<= 1) e2 += __shfl_xor(e2, off);
    float lse = m2 + logf(e2);
    out[(size_t)d * DOUT + c] = v;
    out[(size_t)NN * DOUT + (size_t)d * DOUT + c] = v - lse;
}

extern "C" void kernel_launch(void* const* d_in, const int* in_sizes, int n_in,
                              void* d_out, int out_size, void* d_ws, size_t ws_size,
                              hipStream_t stream) {
    const float* x     = (const float*)d_in[0];
    const int*   ei    = (const int*)d_in[1];
    const float* Wl1   = (const float*)d_in[2];
    const float* Wr1   = (const float*)d_in[3];
    const float* att1  = (const float*)d_in[4];
    const float* bias1 = (const float*)d_in[5];
    const float* Wl2   = (const float*)d_in[6];
    const float* Wr2   = (const float*)d_in[7];
    const float* att2  = (const float*)d_in[8];
    const float* bias2 = (const float*)d_in[9];
    float* out = (float*)d_out;

    // ---- workspace layout ----
    float* xl1    = (float*)d_ws;                    // NN*128
    float* xr1    = xl1 + (size_t)NN * DIN;          // NN*128
    float* hout   = xr1 + (size_t)NN * DIN;          // NN*128
    float* xl2    = hout + (size_t)NN * DIN;         // NN*16
    float* xr2    = xl2 + (size_t)NN * DOUT;         // NN*16
    int*   esrc   = (int*)(xr2 + (size_t)NN * DOUT); // ET
    int*   rowstart = esrc + (size_t)ET;             // NN+1
    // zero-init region:
    int*   cnt    = rowstart + NN + 1;               // NN
    int*   cursor = cnt + NN;                        // NN

    hipMemsetAsync(cnt, 0, (size_t)2 * NN * sizeof(int), stream);

    const int B = 256;
    int gN = (NN + GM - 1) / GM;
    gemm1<<<gN, B, 0, stream>>>(x, Wl1, Wr1, xl1, xr1);

    int gE = (ET + B - 1) / B;
    deg_count<<<gE, B, 0, stream>>>(ei, cnt);
    scan_deg<<<1, 1024, 0, stream>>>(cnt, rowstart);
    fill_csr<<<gE, B, 0, stream>>>(ei, rowstart, cursor, esrc);

    l1_fused<<<NN, 128, 0, stream>>>(esrc, rowstart, xl1, xr1, att1, bias1, hout);

    gemm2<<<gN, B, 0, stream>>>(hout, Wl2, Wr2, xl2, xr2);

    l2_fused<<<(NN + 15) / 16, B, 0, stream>>>(esrc, rowstart, xl2, xr2, att2, bias2, out);
}

// Round 4
// 419.646 us; speedup vs baseline: 17.5616x; 1.2072x over previous
//
#include <hip/hip_runtime.h>
#include <hip/hip_bf16.h>
#include <math.h>

#define NN 50000
#define EE 800000
#define ET 850000   // EE + NN self loops
#define DIN 128
#define HEADS 8
#define DH 16
#define DOUT 16
#define NEG 0.2f
#define GM 32       // nodes per GEMM block

// ---------- layer-1 GEMMs: xl1 = x@Wl1, xr1 = x@Wr1 (register-tiled) ----------
__global__ __launch_bounds__(256) void gemm1(const float* __restrict__ x,
                                             const float* __restrict__ Wl,
                                             const float* __restrict__ Wr,
                                             float* __restrict__ xl, float* __restrict__ xr) {
    __shared__ float xs[GM][DIN];
    int t = threadIdx.x;
    int n0 = blockIdx.x * GM;
    {   // stage 32 x-rows, coalesced float4
        int r = t >> 3, q0 = t & 7;
        int n = n0 + r;
        float4* dstq = (float4*)(xs[r]);
        if (n < NN) {
            const float4* src = (const float4*)(x + (size_t)n * DIN);
#pragma unroll
            for (int k = 0; k < 4; ++k) dstq[q0 + 8 * k] = src[q0 + 8 * k];
        } else {
#pragma unroll
            for (int k = 0; k < 4; ++k) dstq[q0 + 8 * k] = make_float4(0.f, 0.f, 0.f, 0.f);
        }
    }
    __syncthreads();
    int q = t & 63;        // 64 col-quads: 0..31 -> Wl, 32..63 -> Wr
    int g = t >> 6;        // wave-uniform node group (broadcast LDS reads)
    const float* __restrict__ W = (q < 32) ? Wl : Wr;
    int cq = q & 31;
    float4 acc[8];
#pragma unroll
    for (int j = 0; j < 8; ++j) acc[j] = make_float4(0.f, 0.f, 0.f, 0.f);
#pragma unroll 4
    for (int i = 0; i < DIN; ++i) {
        float4 w = ((const float4*)(W + (size_t)i * 128))[cq];
#pragma unroll
        for (int j = 0; j < 8; ++j) {
            float xv = xs[g * 8 + j][i];
            acc[j].x += xv * w.x; acc[j].y += xv * w.y;
            acc[j].z += xv * w.z; acc[j].w += xv * w.w;
        }
    }
    float* __restrict__ dst = (q < 32) ? xl : xr;
#pragma unroll
    for (int j = 0; j < 8; ++j) {
        int n = n0 + g * 8 + j;
        if (n < NN) ((float4*)(dst + (size_t)n * DIN))[cq] = acc[j];
    }
}

// ---------- CSR build ----------
// counts only the EE real edges (self-loops folded into scan as +1/node)
__global__ void deg_count(const int* __restrict__ ei, int* __restrict__ cnt) {
    int i = blockIdx.x * blockDim.x + threadIdx.x;
    if (i >= EE / 4) return;
    int4 dd = ((const int4*)(ei + EE))[i];
    atomicAdd(&cnt[dd.x], 1);
    atomicAdd(&cnt[dd.y], 1);
    atomicAdd(&cnt[dd.z], 1);
    atomicAdd(&cnt[dd.w], 1);
}

__global__ void scan_deg(const int* __restrict__ cnt, int* __restrict__ rowstart) {
    __shared__ int partial[1024];
    int t = threadIdx.x;
    const int C = (NN + 1023) / 1024;  // 49
    int lo = t * C, hi = lo + C; if (hi > NN) hi = NN; if (lo > NN) lo = NN;
    int s = 0;
    for (int i = lo; i < hi; ++i) s += cnt[i] + 1;   // +1: self-loop
    partial[t] = s;
    __syncthreads();
    for (int off = 1; off < 1024; off <<= 1) {
        int v = (t >= off) ? partial[t - off] : 0;
        __syncthreads();
        partial[t] += v;
        __syncthreads();
    }
    int base = (t > 0) ? partial[t - 1] : 0;
    for (int i = lo; i < hi; ++i) { rowstart[i] = base; base += cnt[i] + 1; }
    if (t == 1023) rowstart[NN] = base;   // == ET
}

__global__ void fill_csr(const int* __restrict__ ei, const int* __restrict__ rowstart,
                         int* __restrict__ cursor, int* __restrict__ esrc) {
    int i = blockIdx.x * blockDim.x + threadIdx.x;
    int e0 = i * 4;
    if (e0 >= ET) return;
    if (e0 + 3 < EE) {
        int4 ss = *(const int4*)(ei + e0);
        int4 dd = *(const int4*)(ei + EE + e0);
        int p;
        p = atomicAdd(&cursor[dd.x], 1); esrc[rowstart[dd.x] + p] = ss.x;
        p = atomicAdd(&cursor[dd.y], 1); esrc[rowstart[dd.y] + p] = ss.y;
        p = atomicAdd(&cursor[dd.z], 1); esrc[rowstart[dd.z] + p] = ss.z;
        p = atomicAdd(&cursor[dd.w], 1); esrc[rowstart[dd.w] + p] = ss.w;
    } else {
#pragma unroll
        for (int k = 0; k < 4; ++k) {
            int e = e0 + k;
            if (e >= ET) break;
            int s, d;
            if (e < EE) { s = ei[e]; d = ei[EE + e]; }
            else        { s = e - EE; d = s; }
            int p = atomicAdd(&cursor[d], 1);
            esrc[rowstart[d] + p] = s;
        }
    }
}

// ---------- layer-1 fused: logits + segment softmax + gather + bias + ELU ----------
// one wave per dst (4 dst per 256-block). Lane halves = 2 edge slots; within a
// half, lane q (0..31) owns channel quad [4q..4q+4). Head h = q>>2; logit reduce
// = 4 in-thread FMAs + shfl_xor(1,2). No max subtraction (glorot logits << 88).
__global__ __launch_bounds__(256) void l1_fused(const int* __restrict__ esrc,
                                                const int* __restrict__ rowstart,
                                                const float* __restrict__ xl,
                                                const float* __restrict__ xr,
                                                const float* __restrict__ att,
                                                const float* __restrict__ bias,
                                                float* __restrict__ hout) {
    int d = blockIdx.x * 4 + (threadIdx.x >> 6);    // NN % 4 == 0
    int lane = threadIdx.x & 63;
    int half = lane >> 5;
    int q = lane & 31;
    int rs = rowstart[d], re = rowstart[d + 1];
    float4 xrq = ((const float4*)(xr + (size_t)d * DIN))[q];
    float4 atq = ((const float4*)att)[q];
    float4 acc = make_float4(0.f, 0.f, 0.f, 0.f);
    float l = 0.f;
    for (int slot = rs + half; slot < re; slot += 2) {
        int s = esrc[slot];
        float4 cur = ((const float4*)(xl + (size_t)s * DIN))[q];
        float v0 = cur.x + xrq.x; v0 = fmaxf(v0, NEG * v0);
        float v1 = cur.y + xrq.y; v1 = fmaxf(v1, NEG * v1);
        float v2 = cur.z + xrq.z; v2 = fmaxf(v2, NEG * v2);
        float v3 = cur.w + xrq.w; v3 = fmaxf(v3, NEG * v3);
        float w = atq.x * v0 + atq.y * v1 + atq.z * v2 + atq.w * v3;
        w += __shfl_xor(w, 1);
        w += __shfl_xor(w, 2);          // full 16-ch head logit, replicated in 4 lanes
        float p = __expf(w);
        acc.x += p * cur.x; acc.y += p * cur.y;
        acc.z += p * cur.z; acc.w += p * cur.w;
        l += p;
    }
    // combine the two edge-parity halves (lanes L and L+32 hold same channels)
    acc.x += __shfl_xor(acc.x, 32);
    acc.y += __shfl_xor(acc.y, 32);
    acc.z += __shfl_xor(acc.z, 32);
    acc.w += __shfl_xor(acc.w, 32);
    l += __shfl_xor(l, 32);
    if (half == 0) {
        float inv = 1.f / l;
        float4 b = ((const float4*)bias)[q];
        float4 o;
        o.x = acc.x * inv + b.x; o.x = o.x > 0.f ? o.x : expm1f(o.x);
        o.y = acc.y * inv + b.y; o.y = o.y > 0.f ? o.y : expm1f(o.y);
        o.z = acc.z * inv + b.z; o.z = o.z > 0.f ? o.z : expm1f(o.z);
        o.w = acc.w * inv + b.w; o.w = o.w > 0.f ? o.w : expm1f(o.w);
        ((float4*)(hout + (size_t)d * DIN))[q] = o;
    }
}

// ---------- layer-2 GEMMs (register-tiled, W in L1) ----------
__global__ __launch_bounds__(256) void gemm2(const float* __restrict__ h,
                                             const float* __restrict__ Wl,
                                             const float* __restrict__ Wr,
                                             float* __restrict__ xl, float* __restrict__ xr) {
    __shared__ float xs[GM][DIN + 4];
    int t = threadIdx.x;
    int n0 = blockIdx.x * GM;
    {
        int r = t >> 3, q0 = t & 7;
        int n = n0 + r;
        float4* dstq = (float4*)(xs[r]);
        if (n < NN) {
            const float4* src = (const float4*)(h + (size_t)n * DIN);
#pragma unroll
            for (int k = 0; k < 4; ++k) dstq[q0 + 8 * k] = src[q0 + 8 * k];
        } else {
#pragma unroll
            for (int k = 0; k < 4; ++k) dstq[q0 + 8 * k] = make_float4(0.f, 0.f, 0.f, 0.f);
        }
    }
    __syncthreads();
    int q = t & 7;          // 8 col-quads: 0..3 -> Wl2, 4..7 -> Wr2
    int g = t >> 3;         // node within tile
    const float* __restrict__ W = (q < 4) ? Wl : Wr;
    int cq = q & 3;
    float4 acc = make_float4(0.f, 0.f, 0.f, 0.f);
#pragma unroll 8
    for (int i = 0; i < DIN; ++i) {
        float4 w = ((const float4*)(W + (size_t)i * DOUT))[cq];
        float xv = xs[g][i];
        acc.x += xv * w.x; acc.y += xv * w.y; acc.z += xv * w.z; acc.w += xv * w.w;
    }
    int n = n0 + g;
    if (n < NN) {
        float* __restrict__ dst = (q < 4) ? xl : xr;
        ((float4*)(dst + (size_t)n * DOUT))[cq] = acc;
    }
}

// ---------- layer-2 fused: softmax + gather + bias + log_softmax ----------
// one wave per dst: 16 edge slots x 4 lanes x float4 (16 ch).
__global__ __launch_bounds__(256) void l2_fused(const int* __restrict__ esrc,
                                                const int* __restrict__ rowstart,
                                                const float* __restrict__ xl,
                                                const float* __restrict__ xr,
                                                const float* __restrict__ att,
                                                const float* __restrict__ bias,
                                                float* __restrict__ out) {
    int d = blockIdx.x * 4 + (threadIdx.x >> 6);    // NN % 4 == 0
    int lane = threadIdx.x & 63;
    int sl = lane >> 2;     // edge slot group 0..15
    int q = lane & 3;       // channel quad
    int rs = rowstart[d], re = rowstart[d + 1];
    float4 xrq = ((const float4*)(xr + (size_t)d * DOUT))[q];
    float4 atq = ((const float4*)att)[q];
    float4 acc = make_float4(0.f, 0.f, 0.f, 0.f);
    float l = 0.f;
    for (int slot = rs + sl; slot < re; slot += 16) {
        int s = esrc[slot];
        float4 cur = ((const float4*)(xl + (size_t)s * DOUT))[q];
        float v0 = cur.x + xrq.x; v0 = fmaxf(v0, NEG * v0);
        float v1 = cur.y + xrq.y; v1 = fmaxf(v1, NEG * v1);
        float v2 = cur.z + xrq.z; v2 = fmaxf(v2, NEG * v2);
        float v3 = cur.w + xrq.w; v3 = fmaxf(v3, NEG * v3);
        float w = atq.x * v0 + atq.y * v1 + atq.z * v2 + atq.w * v3;
        w += __shfl_xor(w, 1);
        w += __shfl_xor(w, 2);          // full 16-ch logit
        float p = __expf(w);
        acc.x += p * cur.x; acc.y += p * cur.y;
        acc.z += p * cur.z; acc.w += p * cur.w;
        l += p;
    }
    // reduce across the 16 slot groups
#pragma unroll
    for (int off = 4; off < 64; off <<= 1) {
        acc.x += __shfl_xor(acc.x, off);
        acc.y += __shfl_xor(acc.y, off);
        acc.z += __shfl_xor(acc.z, off);
        acc.w += __shfl_xor(acc.w, off);
        l += __shfl_xor(l, off);
    }
    float inv = 1.f / l;
    float4 b = ((const float4*)bias)[q];
    float4 v;
    v.x = acc.x * inv + b.x; v.y = acc.y * inv + b.y;
    v.z = acc.z * inv + b.z; v.w = acc.w * inv + b.w;
    // log_softmax over the 16 channels (4 in-thread + 4-lane shfl)
    float m = fmaxf(fmaxf(v.x, v.y), fmaxf(v.z, v.w));
    m = fmaxf(m, __shfl_xor(m, 1));
    m = fmaxf(m, __shfl_xor(m, 2));
    float es = __expf(v.x - m) + __expf(v.y - m) + __expf(v.z - m) + __expf(v.w - m);
    es += __shfl_xor(es, 1);
    es += __shfl_xor(es, 2);
    float lse = m + __logf(es);
    if (sl == 0) {
        ((float4*)(out + (size_t)d * DOUT))[q] = v;
        float4 ls;
        ls.x = v.x - lse; ls.y = v.y - lse; ls.z = v.z - lse; ls.w = v.w - lse;
        ((float4*)(out + (size_t)NN * DOUT + (size_t)d * DOUT))[q] = ls;
    }
}

extern "C" void kernel_launch(void* const* d_in, const int* in_sizes, int n_in,
                              void* d_out, int out_size, void* d_ws, size_t ws_size,
                              hipStream_t stream) {
    const float* x     = (const float*)d_in[0];
    const int*   ei    = (const int*)d_in[1];
    const float* Wl1   = (const float*)d_in[2];
    const float* Wr1   = (const float*)d_in[3];
    const float* att1  = (const float*)d_in[4];
    const float* bias1 = (const float*)d_in[5];
    const float* Wl2   = (const float*)d_in[6];
    const float* Wr2   = (const float*)d_in[7];
    const float* att2  = (const float*)d_in[8];
    const float* bias2 = (const float*)d_in[9];
    float* out = (float*)d_out;

    // ---- workspace layout ----
    float* xl1    = (float*)d_ws;                    // NN*128
    float* xr1    = xl1 + (size_t)NN * DIN;          // NN*128
    float* hout   = xr1 + (size_t)NN * DIN;          // NN*128
    float* xl2    = hout + (size_t)NN * DIN;         // NN*16
    float* xr2    = xl2 + (size_t)NN * DOUT;         // NN*16
    int*   esrc   = (int*)(xr2 + (size_t)NN * DOUT); // ET
    int*   rowstart = esrc + (size_t)ET;             // NN+1
    // zero-init region:
    int*   cnt    = rowstart + NN + 1;               // NN
    int*   cursor = cnt + NN;                        // NN

    hipMemsetAsync(cnt, 0, (size_t)2 * NN * sizeof(int), stream);

    const int B = 256;
    int gN = (NN + GM - 1) / GM;
    gemm1<<<gN, B, 0, stream>>>(x, Wl1, Wr1, xl1, xr1);

    deg_count<<<(EE / 4 + B - 1) / B, B, 0, stream>>>(ei, cnt);
    scan_deg<<<1, 1024, 0, stream>>>(cnt, rowstart);
    fill_csr<<<(ET / 4 + B - 1) / B, B, 0, stream>>>(ei, rowstart, cursor, esrc);

    l1_fused<<<NN / 4, B, 0, stream>>>(esrc, rowstart, xl1, xr1, att1, bias1, hout);

    gemm2<<<gN, B, 0, stream>>>(hout, Wl2, Wr2, xl2, xr2);

    l2_fused<<<NN / 4, B, 0, stream>>>(esrc, rowstart, xl2, xr2, att2, bias2, out);
}

// Round 5
// 350.938 us; speedup vs baseline: 20.9999x; 1.1958x over previous
//
#include <hip/hip_runtime.h>
#include <hip/hip_bf16.h>
#include <math.h>

#define NN 50000
#define EE 800000
#define ET 850000   // EE + NN self loops
#define DIN 128
#define HEADS 8
#define DH 16
#define DOUT 16
#define NEG 0.2f
#define GM 32       // nodes per GEMM block
#define SCH 256     // scan chunk size
#define NB ((NN + SCH - 1) / SCH)   // 196 scan blocks (must be <= 256)

// ---------- layer-1 GEMMs: xl1 = x@Wl1, xr1 = x@Wr1 (register-tiled) ----------
__global__ __launch_bounds__(256) void gemm1(const float* __restrict__ x,
                                             const float* __restrict__ Wl,
                                             const float* __restrict__ Wr,
                                             float* __restrict__ xl, float* __restrict__ xr) {
    __shared__ float xs[GM][DIN];
    int t = threadIdx.x;
    int n0 = blockIdx.x * GM;
    {   // stage 32 x-rows, coalesced float4
        int r = t >> 3, q0 = t & 7;
        int n = n0 + r;
        float4* dstq = (float4*)(xs[r]);
        if (n < NN) {
            const float4* src = (const float4*)(x + (size_t)n * DIN);
#pragma unroll
            for (int k = 0; k < 4; ++k) dstq[q0 + 8 * k] = src[q0 + 8 * k];
        } else {
#pragma unroll
            for (int k = 0; k < 4; ++k) dstq[q0 + 8 * k] = make_float4(0.f, 0.f, 0.f, 0.f);
        }
    }
    __syncthreads();
    int q = t & 63;        // 64 col-quads: 0..31 -> Wl, 32..63 -> Wr
    int g = t >> 6;        // wave-uniform node group (broadcast LDS reads)
    const float* __restrict__ W = (q < 32) ? Wl : Wr;
    int cq = q & 31;
    float4 acc[8];
#pragma unroll
    for (int j = 0; j < 8; ++j) acc[j] = make_float4(0.f, 0.f, 0.f, 0.f);
#pragma unroll 4
    for (int i = 0; i < DIN; ++i) {
        float4 w = ((const float4*)(W + (size_t)i * 128))[cq];
#pragma unroll
        for (int j = 0; j < 8; ++j) {
            float xv = xs[g * 8 + j][i];
            acc[j].x += xv * w.x; acc[j].y += xv * w.y;
            acc[j].z += xv * w.z; acc[j].w += xv * w.w;
        }
    }
    float* __restrict__ dst = (q < 32) ? xl : xr;
#pragma unroll
    for (int j = 0; j < 8; ++j) {
        int n = n0 + g * 8 + j;
        if (n < NN) ((float4*)(dst + (size_t)n * DIN))[cq] = acc[j];
    }
}

// ---------- CSR build ----------
// counts only the EE real edges (self-loops folded into scan as +1/node)
__global__ void deg_count(const int* __restrict__ ei, int* __restrict__ cnt) {
    int i = blockIdx.x * blockDim.x + threadIdx.x;
    if (i >= EE / 4) return;
    int4 dd = ((const int4*)(ei + EE))[i];
    atomicAdd(&cnt[dd.x], 1);
    atomicAdd(&cnt[dd.y], 1);
    atomicAdd(&cnt[dd.z], 1);
    atomicAdd(&cnt[dd.w], 1);
}

// ---- hierarchical exclusive scan of (cnt[i]+1) over NN entries ----
__global__ __launch_bounds__(256) void block_sums(const int* __restrict__ cnt,
                                                  int* __restrict__ bsum) {
    __shared__ int red[256];
    int b = blockIdx.x, t = threadIdx.x;
    int i = b * SCH + t;
    red[t] = (i < NN) ? cnt[i] + 1 : 0;
    __syncthreads();
#pragma unroll
    for (int off = 128; off > 0; off >>= 1) {
        if (t < off) red[t] += red[t + off];
        __syncthreads();
    }
    if (t == 0) bsum[b] = red[0];
}

__global__ __launch_bounds__(256) void scan_bsums(const int* __restrict__ bsum,
                                                  int* __restrict__ boff) {
    __shared__ int sh[256];
    int t = threadIdx.x;
    int v = (t < NB) ? bsum[t] : 0;
    sh[t] = v;
    __syncthreads();
    for (int off = 1; off < 256; off <<= 1) {
        int u = (t >= off) ? sh[t - off] : 0;
        __syncthreads();
        sh[t] += u;
        __syncthreads();
    }
    if (t < NB) boff[t] = sh[t] - v;   // exclusive block offsets
}

__global__ __launch_bounds__(256) void write_rowstart(const int* __restrict__ cnt,
                                                      const int* __restrict__ boff,
                                                      int* __restrict__ rowstart) {
    __shared__ int sh[256];
    int b = blockIdx.x, t = threadIdx.x;
    int i = b * SCH + t;
    int v = (i < NN) ? cnt[i] + 1 : 0;
    sh[t] = v;
    __syncthreads();
    for (int off = 1; off < 256; off <<= 1) {
        int u = (t >= off) ? sh[t - off] : 0;
        __syncthreads();
        sh[t] += u;
        __syncthreads();
    }
    if (i <= NN) rowstart[i] = boff[b] + sh[t] - v;   // i==NN -> ET
}

__global__ void fill_csr(const int* __restrict__ ei, const int* __restrict__ rowstart,
                         int* __restrict__ cursor, int* __restrict__ esrc) {
    int i = blockIdx.x * blockDim.x + threadIdx.x;
    int e0 = i * 4;
    if (e0 >= ET) return;
    if (e0 + 3 < EE) {
        int4 ss = *(const int4*)(ei + e0);
        int4 dd = *(const int4*)(ei + EE + e0);
        int p;
        p = atomicAdd(&cursor[dd.x], 1); esrc[rowstart[dd.x] + p] = ss.x;
        p = atomicAdd(&cursor[dd.y], 1); esrc[rowstart[dd.y] + p] = ss.y;
        p = atomicAdd(&cursor[dd.z], 1); esrc[rowstart[dd.z] + p] = ss.z;
        p = atomicAdd(&cursor[dd.w], 1); esrc[rowstart[dd.w] + p] = ss.w;
    } else {
#pragma unroll
        for (int k = 0; k < 4; ++k) {
            int e = e0 + k;
            if (e >= ET) break;
            int s, d;
            if (e < EE) { s = ei[e]; d = ei[EE + e]; }
            else        { s = e - EE; d = s; }
            int p = atomicAdd(&cursor[d], 1);
            esrc[rowstart[d] + p] = s;
        }
    }
}

// ---------- layer-1 fused: logits + segment softmax + gather + bias + ELU ----------
// one wave per dst (4 dst per 256-block). Lane halves = 2 edge slots; within a
// half, lane q (0..31) owns channel quad [4q..4q+4). Head h = q>>2; logit reduce
// = 4 in-thread FMAs + shfl_xor(1,2). No max subtraction (glorot logits << 88).
__global__ __launch_bounds__(256) void l1_fused(const int* __restrict__ esrc,
                                                const int* __restrict__ rowstart,
                                                const float* __restrict__ xl,
                                                const float* __restrict__ xr,
                                                const float* __restrict__ att,
                                                const float* __restrict__ bias,
                                                float* __restrict__ hout) {
    int d = blockIdx.x * 4 + (threadIdx.x >> 6);    // NN % 4 == 0
    int lane = threadIdx.x & 63;
    int half = lane >> 5;
    int q = lane & 31;
    int rs = rowstart[d], re = rowstart[d + 1];
    float4 xrq = ((const float4*)(xr + (size_t)d * DIN))[q];
    float4 atq = ((const float4*)att)[q];
    float4 acc = make_float4(0.f, 0.f, 0.f, 0.f);
    float l = 0.f;
    for (int slot = rs + half; slot < re; slot += 2) {
        int s = esrc[slot];
        float4 cur = ((const float4*)(xl + (size_t)s * DIN))[q];
        float v0 = cur.x + xrq.x; v0 = fmaxf(v0, NEG * v0);
        float v1 = cur.y + xrq.y; v1 = fmaxf(v1, NEG * v1);
        float v2 = cur.z + xrq.z; v2 = fmaxf(v2, NEG * v2);
        float v3 = cur.w + xrq.w; v3 = fmaxf(v3, NEG * v3);
        float w = atq.x * v0 + atq.y * v1 + atq.z * v2 + atq.w * v3;
        w += __shfl_xor(w, 1);
        w += __shfl_xor(w, 2);          // full 16-ch head logit, replicated in 4 lanes
        float p = __expf(w);
        acc.x += p * cur.x; acc.y += p * cur.y;
        acc.z += p * cur.z; acc.w += p * cur.w;
        l += p;
    }
    // combine the two edge-parity halves (lanes L and L+32 hold same channels)
    acc.x += __shfl_xor(acc.x, 32);
    acc.y += __shfl_xor(acc.y, 32);
    acc.z += __shfl_xor(acc.z, 32);
    acc.w += __shfl_xor(acc.w, 32);
    l += __shfl_xor(l, 32);
    if (half == 0) {
        float inv = 1.f / l;
        float4 b = ((const float4*)bias)[q];
        float4 o;
        o.x = acc.x * inv + b.x; o.x = o.x > 0.f ? o.x : expm1f(o.x);
        o.y = acc.y * inv + b.y; o.y = o.y > 0.f ? o.y : expm1f(o.y);
        o.z = acc.z * inv + b.z; o.z = o.z > 0.f ? o.z : expm1f(o.z);
        o.w = acc.w * inv + b.w; o.w = o.w > 0.f ? o.w : expm1f(o.w);
        ((float4*)(hout + (size_t)d * DIN))[q] = o;
    }
}

// ---------- layer-2 GEMMs (register-tiled, W in L1) ----------
__global__ __launch_bounds__(256) void gemm2(const float* __restrict__ h,
                                             const float* __restrict__ Wl,
                                             const float* __restrict__ Wr,
                                             float* __restrict__ xl, float* __restrict__ xr) {
    __shared__ float xs[GM][DIN + 4];
    int t = threadIdx.x;
    int n0 = blockIdx.x * GM;
    {
        int r = t >> 3, q0 = t & 7;
        int n = n0 + r;
        float4* dstq = (float4*)(xs[r]);
        if (n < NN) {
            const float4* src = (const float4*)(h + (size_t)n * DIN);
#pragma unroll
            for (int k = 0; k < 4; ++k) dstq[q0 + 8 * k] = src[q0 + 8 * k];
        } else {
#pragma unroll
            for (int k = 0; k < 4; ++k) dstq[q0 + 8 * k] = make_float4(0.f, 0.f, 0.f, 0.f);
        }
    }
    __syncthreads();
    int q = t & 7;          // 8 col-quads: 0..3 -> Wl2, 4..7 -> Wr2
    int g = t >> 3;         // node within tile
    const float* __restrict__ W = (q < 4) ? Wl : Wr;
    int cq = q & 3;
    float4 acc = make_float4(0.f, 0.f, 0.f, 0.f);
#pragma unroll 8
    for (int i = 0; i < DIN; ++i) {
        float4 w = ((const float4*)(W + (size_t)i * DOUT))[cq];
        float xv = xs[g][i];
        acc.x += xv * w.x; acc.y += xv * w.y; acc.z += xv * w.z; acc.w += xv * w.w;
    }
    int n = n0 + g;
    if (n < NN) {
        float* __restrict__ dst = (q < 4) ? xl : xr;
        ((float4*)(dst + (size_t)n * DOUT))[cq] = acc;
    }
}

// ---------- layer-2 fused: softmax + gather + bias + log_softmax ----------
// one wave per dst: 16 edge slots x 4 lanes x float4 (16 ch).
__global__ __launch_bounds__(256) void l2_fused(const int* __restrict__ esrc,
                                                const int* __restrict__ rowstart,
                                                const float* __restrict__ xl,
                                                const float* __restrict__ xr,
                                                const float* __restrict__ att,
                                                const float* __restrict__ bias,
                                                float* __restrict__ out) {
    int d = blockIdx.x * 4 + (threadIdx.x >> 6);    // NN % 4 == 0
    int lane = threadIdx.x & 63;
    int sl = lane >> 2;     // edge slot group 0..15
    int q = lane & 3;       // channel quad
    int rs = rowstart[d], re = rowstart[d + 1];
    float4 xrq = ((const float4*)(xr + (size_t)d * DOUT))[q];
    float4 atq = ((const float4*)att)[q];
    float4 acc = make_float4(0.f, 0.f, 0.f, 0.f);
    float l = 0.f;
    for (int slot = rs + sl; slot < re; slot += 16) {
        int s = esrc[slot];
        float4 cur = ((const float4*)(xl + (size_t)s * DOUT))[q];
        float v0 = cur.x + xrq.x; v0 = fmaxf(v0, NEG * v0);
        float v1 = cur.y + xrq.y; v1 = fmaxf(v1, NEG * v1);
        float v2 = cur.z + xrq.z; v2 = fmaxf(v2, NEG * v2);
        float v3 = cur.w + xrq.w; v3 = fmaxf(v3, NEG * v3);
        float w = atq.x * v0 + atq.y * v1 + atq.z * v2 + atq.w * v3;
        w += __shfl_xor(w, 1);
        w += __shfl_xor(w, 2);          // full 16-ch logit
        float p = __expf(w);
        acc.x += p * cur.x; acc.y += p * cur.y;
        acc.z += p * cur.z; acc.w += p * cur.w;
        l += p;
    }
    // reduce across the 16 slot groups
#pragma unroll
    for (int off = 4; off < 64; off <<= 1) {
        acc.x += __shfl_xor(acc.x, off);
        acc.y += __shfl_xor(acc.y, off);
        acc.z += __shfl_xor(acc.z, off);
        acc.w += __shfl_xor(acc.w, off);
        l += __shfl_xor(l, off);
    }
    float inv = 1.f / l;
    float4 b = ((const float4*)bias)[q];
    float4 v;
    v.x = acc.x * inv + b.x; v.y = acc.y * inv + b.y;
    v.z = acc.z * inv + b.z; v.w = acc.w * inv + b.w;
    // log_softmax over the 16 channels (4 in-thread + 4-lane shfl)
    float m = fmaxf(fmaxf(v.x, v.y), fmaxf(v.z, v.w));
    m = fmaxf(m, __shfl_xor(m, 1));
    m = fmaxf(m, __shfl_xor(m, 2));
    float es = __expf(v.x - m) + __expf(v.y - m) + __expf(v.z - m) + __expf(v.w - m);
    es += __shfl_xor(es, 1);
    es += __shfl_xor(es, 2);
    float lse = m + __logf(es);
    if (sl == 0) {
        ((float4*)(out + (size_t)d * DOUT))[q] = v;
        float4 ls;
        ls.x = v.x - lse; ls.y = v.y - lse; ls.z = v.z - lse; ls.w = v.w - lse;
        ((float4*)(out + (size_t)NN * DOUT + (size_t)d * DOUT))[q] = ls;
    }
}

extern "C" void kernel_launch(void* const* d_in, const int* in_sizes, int n_in,
                              void* d_out, int out_size, void* d_ws, size_t ws_size,
                              hipStream_t stream) {
    const float* x     = (const float*)d_in[0];
    const int*   ei    = (const int*)d_in[1];
    const float* Wl1   = (const float*)d_in[2];
    const float* Wr1   = (const float*)d_in[3];
    const float* att1  = (const float*)d_in[4];
    const float* bias1 = (const float*)d_in[5];
    const float* Wl2   = (const float*)d_in[6];
    const float* Wr2   = (const float*)d_in[7];
    const float* att2  = (const float*)d_in[8];
    const float* bias2 = (const float*)d_in[9];
    float* out = (float*)d_out;

    // ---- workspace layout ----
    float* xl1    = (float*)d_ws;                    // NN*128
    float* xr1    = xl1 + (size_t)NN * DIN;          // NN*128
    float* hout   = xr1 + (size_t)NN * DIN;          // NN*128
    float* xl2    = hout + (size_t)NN * DIN;         // NN*16
    float* xr2    = xl2 + (size_t)NN * DOUT;         // NN*16
    int*   esrc   = (int*)(xr2 + (size_t)NN * DOUT); // ET
    int*   rowstart = esrc + (size_t)ET;             // NN+1
    int*   bsum   = rowstart + NN + 1;               // NB
    int*   boff   = bsum + NB;                       // NB
    // zero-init region:
    int*   cnt    = boff + NB;                       // NN
    int*   cursor = cnt + NN;                        // NN

    hipMemsetAsync(cnt, 0, (size_t)2 * NN * sizeof(int), stream);

    const int B = 256;
    int gN = (NN + GM - 1) / GM;
    gemm1<<<gN, B, 0, stream>>>(x, Wl1, Wr1, xl1, xr1);

    deg_count<<<(EE / 4 + B - 1) / B, B, 0, stream>>>(ei, cnt);
    block_sums<<<NB, B, 0, stream>>>(cnt, bsum);
    scan_bsums<<<1, B, 0, stream>>>(bsum, boff);
    write_rowstart<<<NB, B, 0, stream>>>(cnt, boff, rowstart);
    fill_csr<<<(ET / 4 + B - 1) / B, B, 0, stream>>>(ei, rowstart, cursor, esrc);

    l1_fused<<<NN / 4, B, 0, stream>>>(esrc, rowstart, xl1, xr1, att1, bias1, hout);

    gemm2<<<gN, B, 0, stream>>>(hout, Wl2, Wr2, xl2, xr2);

    l2_fused<<<NN / 4, B, 0, stream>>>(esrc, rowstart, xl2, xr2, att2, bias2, out);
}

// Round 6
// 350.133 us; speedup vs baseline: 21.0482x; 1.0023x over previous
//
#include <hip/hip_runtime.h>
#include <hip/hip_bf16.h>
#include <math.h>

#define NN 50000
#define EE 800000
#define ET 850000   // EE + NN self loops
#define DIN 128
#define HEADS 8
#define DH 16
#define DOUT 16
#define NEG 0.2f
#define GM 32       // nodes per GEMM block
#define SCH 256     // scan chunk size
#define NB ((NN + SCH - 1) / SCH)   // 196 scan blocks (must be <= 256)

// ---------- layer-1 GEMMs: xl1 = x@Wl1, xr1 = x@Wr1 (register-tiled) ----------
__global__ __launch_bounds__(256) void gemm1(const float* __restrict__ x,
                                             const float* __restrict__ Wl,
                                             const float* __restrict__ Wr,
                                             float* __restrict__ xl, float* __restrict__ xr) {
    __shared__ float xs[GM][DIN];
    int t = threadIdx.x;
    int n0 = blockIdx.x * GM;
    {   // stage 32 x-rows, coalesced float4
        int r = t >> 3, q0 = t & 7;
        int n = n0 + r;
        float4* dstq = (float4*)(xs[r]);
        if (n < NN) {
            const float4* src = (const float4*)(x + (size_t)n * DIN);
#pragma unroll
            for (int k = 0; k < 4; ++k) dstq[q0 + 8 * k] = src[q0 + 8 * k];
        } else {
#pragma unroll
            for (int k = 0; k < 4; ++k) dstq[q0 + 8 * k] = make_float4(0.f, 0.f, 0.f, 0.f);
        }
    }
    __syncthreads();
    int q = t & 63;        // 64 col-quads: 0..31 -> Wl, 32..63 -> Wr
    int g = t >> 6;        // wave-uniform node group (broadcast LDS reads)
    const float* __restrict__ W = (q < 32) ? Wl : Wr;
    int cq = q & 31;
    float4 acc[8];
#pragma unroll
    for (int j = 0; j < 8; ++j) acc[j] = make_float4(0.f, 0.f, 0.f, 0.f);
#pragma unroll 4
    for (int i = 0; i < DIN; ++i) {
        float4 w = ((const float4*)(W + (size_t)i * 128))[cq];
#pragma unroll
        for (int j = 0; j < 8; ++j) {
            float xv = xs[g * 8 + j][i];
            acc[j].x += xv * w.x; acc[j].y += xv * w.y;
            acc[j].z += xv * w.z; acc[j].w += xv * w.w;
        }
    }
    float* __restrict__ dst = (q < 32) ? xl : xr;
#pragma unroll
    for (int j = 0; j < 8; ++j) {
        int n = n0 + g * 8 + j;
        if (n < NN) ((float4*)(dst + (size_t)n * DIN))[cq] = acc[j];
    }
}

// ---------- CSR build ----------
// counts only the EE real edges (self-loops folded into scan as +1/node)
__global__ void deg_count(const int* __restrict__ ei, int* __restrict__ cnt) {
    int i = blockIdx.x * blockDim.x + threadIdx.x;
    if (i >= EE / 4) return;
    int4 dd = ((const int4*)(ei + EE))[i];
    atomicAdd(&cnt[dd.x], 1);
    atomicAdd(&cnt[dd.y], 1);
    atomicAdd(&cnt[dd.z], 1);
    atomicAdd(&cnt[dd.w], 1);
}

// ---- hierarchical exclusive scan of (cnt[i]+1) over NN entries ----
__global__ __launch_bounds__(256) void block_sums(const int* __restrict__ cnt,
                                                  int* __restrict__ bsum) {
    __shared__ int red[256];
    int b = blockIdx.x, t = threadIdx.x;
    int i = b * SCH + t;
    red[t] = (i < NN) ? cnt[i] + 1 : 0;
    __syncthreads();
#pragma unroll
    for (int off = 128; off > 0; off >>= 1) {
        if (t < off) red[t] += red[t + off];
        __syncthreads();
    }
    if (t == 0) bsum[b] = red[0];
}

__global__ __launch_bounds__(256) void scan_bsums(const int* __restrict__ bsum,
                                                  int* __restrict__ boff) {
    __shared__ int sh[256];
    int t = threadIdx.x;
    int v = (t < NB) ? bsum[t] : 0;
    sh[t] = v;
    __syncthreads();
    for (int off = 1; off < 256; off <<= 1) {
        int u = (t >= off) ? sh[t - off] : 0;
        __syncthreads();
        sh[t] += u;
        __syncthreads();
    }
    if (t < NB) boff[t] = sh[t] - v;   // exclusive block offsets
}

// writes rowstart AND the self-loop entry esrc[rowstart[i]] = i
__global__ __launch_bounds__(256) void write_rowstart(const int* __restrict__ cnt,
                                                      const int* __restrict__ boff,
                                                      int* __restrict__ rowstart,
                                                      int* __restrict__ esrc) {
    __shared__ int sh[256];
    int b = blockIdx.x, t = threadIdx.x;
    int i = b * SCH + t;
    int v = (i < NN) ? cnt[i] + 1 : 0;
    sh[t] = v;
    __syncthreads();
    for (int off = 1; off < 256; off <<= 1) {
        int u = (t >= off) ? sh[t - off] : 0;
        __syncthreads();
        sh[t] += u;
        __syncthreads();
    }
    int pos = boff[b] + sh[t] - v;
    if (i <= NN) rowstart[i] = pos;   // i==NN -> ET
    if (i < NN)  esrc[pos] = i;       // self-loop at slot 0 of each row
}

// real edges only; slot = rowstart[d] + 1 + cursor (self-loop owns slot 0)
__global__ void fill_csr(const int* __restrict__ ei, const int* __restrict__ rowstart,
                         int* __restrict__ cursor, int* __restrict__ esrc) {
    int i = blockIdx.x * blockDim.x + threadIdx.x;
    if (i >= EE / 4) return;     // EE % 4 == 0
    int4 ss = ((const int4*)ei)[i];
    int4 dd = ((const int4*)(ei + EE))[i];
    int p;
    p = atomicAdd(&cursor[dd.x], 1); esrc[rowstart[dd.x] + 1 + p] = ss.x;
    p = atomicAdd(&cursor[dd.y], 1); esrc[rowstart[dd.y] + 1 + p] = ss.y;
    p = atomicAdd(&cursor[dd.z], 1); esrc[rowstart[dd.z] + 1 + p] = ss.z;
    p = atomicAdd(&cursor[dd.w], 1); esrc[rowstart[dd.w] + 1 + p] = ss.w;
}

// ---------- layer-1 fused: logits + segment softmax + gather + bias + ELU ----------
// one wave per dst (4 dst per 256-block). Lane halves = 2 edge slots/iter; lane q
// (0..31) owns channel quad [4q..4q+4). Software pipeline: esrc 2 slots ahead,
// xl row 1 slot ahead (branch-free via clamp to re-1) — breaks the serial
// esrc->row->compute chain that left VALUBusy at 51% in round 5.
__global__ __launch_bounds__(256) void l1_fused(const int* __restrict__ esrc,
                                                const int* __restrict__ rowstart,
                                                const float* __restrict__ xl,
                                                const float* __restrict__ xr,
                                                const float* __restrict__ att,
                                                const float* __restrict__ bias,
                                                float* __restrict__ hout) {
    int d = blockIdx.x * 4 + (threadIdx.x >> 6);    // NN % 4 == 0
    int lane = threadIdx.x & 63;
    int half = lane >> 5;
    int q = lane & 31;
    int rs = rowstart[d], re = rowstart[d + 1];     // re-rs >= 1 (self-loop)
    int last = re - 1;
    float4 xrq = ((const float4*)(xr + (size_t)d * DIN))[q];
    float4 atq = ((const float4*)att)[q];
    float4 acc = make_float4(0.f, 0.f, 0.f, 0.f);
    float l = 0.f;
    int slot = rs + half;
    int c0 = slot < last ? slot : last;
    int s0 = esrc[c0];
    int c1 = slot + 2 < last ? slot + 2 : last;
    int s1 = esrc[c1];
    float4 row = ((const float4*)(xl + (size_t)s0 * DIN))[q];
    for (; slot < re; slot += 2) {
        float4 cur = row;
        int c2 = slot + 4 < last ? slot + 4 : last;
        int s2 = esrc[c2];                                   // 2 ahead
        row = ((const float4*)(xl + (size_t)s1 * DIN))[q];   // 1 ahead
        s1 = s2;
        float v0 = cur.x + xrq.x; v0 = fmaxf(v0, NEG * v0);
        float v1 = cur.y + xrq.y; v1 = fmaxf(v1, NEG * v1);
        float v2 = cur.z + xrq.z; v2 = fmaxf(v2, NEG * v2);
        float v3 = cur.w + xrq.w; v3 = fmaxf(v3, NEG * v3);
        float w = atq.x * v0 + atq.y * v1 + atq.z * v2 + atq.w * v3;
        w += __shfl_xor(w, 1);
        w += __shfl_xor(w, 2);          // full 16-ch head logit, replicated in 4 lanes
        float p = __expf(w);
        acc.x += p * cur.x; acc.y += p * cur.y;
        acc.z += p * cur.z; acc.w += p * cur.w;
        l += p;
    }
    // combine the two edge-parity halves (lanes L and L+32 hold same channels)
    acc.x += __shfl_xor(acc.x, 32);
    acc.y += __shfl_xor(acc.y, 32);
    acc.z += __shfl_xor(acc.z, 32);
    acc.w += __shfl_xor(acc.w, 32);
    l += __shfl_xor(l, 32);
    if (half == 0) {
        float inv = 1.f / l;
        float4 b = ((const float4*)bias)[q];
        float4 o;
        o.x = acc.x * inv + b.x; o.x = o.x > 0.f ? o.x : expm1f(o.x);
        o.y = acc.y * inv + b.y; o.y = o.y > 0.f ? o.y : expm1f(o.y);
        o.z = acc.z * inv + b.z; o.z = o.z > 0.f ? o.z : expm1f(o.z);
        o.w = acc.w * inv + b.w; o.w = o.w > 0.f ? o.w : expm1f(o.w);
        ((float4*)(hout + (size_t)d * DIN))[q] = o;
    }
}

// ---------- layer-2 GEMMs (register-tiled, W in L1) ----------
__global__ __launch_bounds__(256) void gemm2(const float* __restrict__ h,
                                             const float* __restrict__ Wl,
                                             const float* __restrict__ Wr,
                                             float* __restrict__ xl, float* __restrict__ xr) {
    __shared__ float xs[GM][DIN + 4];
    int t = threadIdx.x;
    int n0 = blockIdx.x * GM;
    {
        int r = t >> 3, q0 = t & 7;
        int n = n0 + r;
        float4* dstq = (float4*)(xs[r]);
        if (n < NN) {
            const float4* src = (const float4*)(h + (size_t)n * DIN);
#pragma unroll
            for (int k = 0; k < 4; ++k) dstq[q0 + 8 * k] = src[q0 + 8 * k];
        } else {
#pragma unroll
            for (int k = 0; k < 4; ++k) dstq[q0 + 8 * k] = make_float4(0.f, 0.f, 0.f, 0.f);
        }
    }
    __syncthreads();
    int q = t & 7;          // 8 col-quads: 0..3 -> Wl2, 4..7 -> Wr2
    int g = t >> 3;         // node within tile
    const float* __restrict__ W = (q < 4) ? Wl : Wr;
    int cq = q & 3;
    float4 acc = make_float4(0.f, 0.f, 0.f, 0.f);
#pragma unroll 8
    for (int i = 0; i < DIN; ++i) {
        float4 w = ((const float4*)(W + (size_t)i * DOUT))[cq];
        float xv = xs[g][i];
        acc.x += xv * w.x; acc.y += xv * w.y; acc.z += xv * w.z; acc.w += xv * w.w;
    }
    int n = n0 + g;
    if (n < NN) {
        float* __restrict__ dst = (q < 4) ? xl : xr;
        ((float4*)(dst + (size_t)n * DOUT))[cq] = acc;
    }
}

// ---------- layer-2 fused: softmax + gather + bias + log_softmax ----------
// one wave per dst: 16 edge slots x 4 lanes x float4 (16 ch); esrc prefetched.
__global__ __launch_bounds__(256) void l2_fused(const int* __restrict__ esrc,
                                                const int* __restrict__ rowstart,
                                                const float* __restrict__ xl,
                                                const float* __restrict__ xr,
                                                const float* __restrict__ att,
                                                const float* __restrict__ bias,
                                                float* __restrict__ out) {
    int d = blockIdx.x * 4 + (threadIdx.x >> 6);    // NN % 4 == 0
    int lane = threadIdx.x & 63;
    int sl = lane >> 2;     // edge slot group 0..15
    int q = lane & 3;       // channel quad
    int rs = rowstart[d], re = rowstart[d + 1];
    int last = re - 1;
    float4 xrq = ((const float4*)(xr + (size_t)d * DOUT))[q];
    float4 atq = ((const float4*)att)[q];
    float4 acc = make_float4(0.f, 0.f, 0.f, 0.f);
    float l = 0.f;
    int slot = rs + sl;
    int c0 = slot < last ? slot : last;
    int s0 = esrc[c0];
    for (; slot < re; slot += 16) {
        int c1 = slot + 16 < last ? slot + 16 : last;
        int s1 = esrc[c1];
        float4 cur = ((const float4*)(xl + (size_t)s0 * DOUT))[q];
        s0 = s1;
        float v0 = cur.x + xrq.x; v0 = fmaxf(v0, NEG * v0);
        float v1 = cur.y + xrq.y; v1 = fmaxf(v1, NEG * v1);
        float v2 = cur.z + xrq.z; v2 = fmaxf(v2, NEG * v2);
        float v3 = cur.w + xrq.w; v3 = fmaxf(v3, NEG * v3);
        float w = atq.x * v0 + atq.y * v1 + atq.z * v2 + atq.w * v3;
        w += __shfl_xor(w, 1);
        w += __shfl_xor(w, 2);          // full 16-ch logit
        float p = __expf(w);
        acc.x += p * cur.x; acc.y += p * cur.y;
        acc.z += p * cur.z; acc.w += p * cur.w;
        l += p;
    }
    // reduce across the 16 slot groups
#pragma unroll
    for (int off = 4; off < 64; off <<= 1) {
        acc.x += __shfl_xor(acc.x, off);
        acc.y += __shfl_xor(acc.y, off);
        acc.z += __shfl_xor(acc.z, off);
        acc.w += __shfl_xor(acc.w, off);
        l += __shfl_xor(l, off);
    }
    float inv = 1.f / l;
    float4 b = ((const float4*)bias)[q];
    float4 v;
    v.x = acc.x * inv + b.x; v.y = acc.y * inv + b.y;
    v.z = acc.z * inv + b.z; v.w = acc.w * inv + b.w;
    // log_softmax over the 16 channels (4 in-thread + 4-lane shfl)
    float m = fmaxf(fmaxf(v.x, v.y), fmaxf(v.z, v.w));
    m = fmaxf(m, __shfl_xor(m, 1));
    m = fmaxf(m, __shfl_xor(m, 2));
    float es = __expf(v.x - m) + __expf(v.y - m) + __expf(v.z - m) + __expf(v.w - m);
    es += __shfl_xor(es, 1);
    es += __shfl_xor(es, 2);
    float lse = m + __logf(es);
    if (sl == 0) {
        ((float4*)(out + (size_t)d * DOUT))[q] = v;
        float4 ls;
        ls.x = v.x - lse; ls.y = v.y - lse; ls.z = v.z - lse; ls.w = v.w - lse;
        ((float4*)(out + (size_t)NN * DOUT + (size_t)d * DOUT))[q] = ls;
    }
}

extern "C" void kernel_launch(void* const* d_in, const int* in_sizes, int n_in,
                              void* d_out, int out_size, void* d_ws, size_t ws_size,
                              hipStream_t stream) {
    const float* x     = (const float*)d_in[0];
    const int*   ei    = (const int*)d_in[1];
    const float* Wl1   = (const float*)d_in[2];
    const float* Wr1   = (const float*)d_in[3];
    const float* att1  = (const float*)d_in[4];
    const float* bias1 = (const float*)d_in[5];
    const float* Wl2   = (const float*)d_in[6];
    const float* Wr2   = (const float*)d_in[7];
    const float* att2  = (const float*)d_in[8];
    const float* bias2 = (const float*)d_in[9];
    float* out = (float*)d_out;

    // ---- workspace layout ----
    float* xl1    = (float*)d_ws;                    // NN*128
    float* xr1    = xl1 + (size_t)NN * DIN;          // NN*128
    float* hout   = xr1 + (size_t)NN * DIN;          // NN*128
    float* xl2    = hout + (size_t)NN * DIN;         // NN*16
    float* xr2    = xl2 + (size_t)NN * DOUT;         // NN*16
    int*   esrc   = (int*)(xr2 + (size_t)NN * DOUT); // ET
    int*   rowstart = esrc + (size_t)ET;             // NN+1
    int*   bsum   = rowstart + NN + 1;               // NB
    int*   boff   = bsum + NB;                       // NB
    // zero-init region:
    int*   cnt    = boff + NB;                       // NN
    int*   cursor = cnt + NN;                        // NN

    hipMemsetAsync(cnt, 0, (size_t)2 * NN * sizeof(int), stream);

    const int B = 256;
    int gN = (NN + GM - 1) / GM;
    gemm1<<<gN, B, 0, stream>>>(x, Wl1, Wr1, xl1, xr1);

    deg_count<<<(EE / 4 + B - 1) / B, B, 0, stream>>>(ei, cnt);
    block_sums<<<NB, B, 0, stream>>>(cnt, bsum);
    scan_bsums<<<1, B, 0, stream>>>(bsum, boff);
    write_rowstart<<<NB, B, 0, stream>>>(cnt, boff, rowstart, esrc);
    fill_csr<<<(EE / 4 + B - 1) / B, B, 0, stream>>>(ei, rowstart, cursor, esrc);

    l1_fused<<<NN / 4, B, 0, stream>>>(esrc, rowstart, xl1, xr1, att1, bias1, hout);

    gemm2<<<gN, B, 0, stream>>>(hout, Wl2, Wr2, xl2, xr2);

    l2_fused<<<NN / 4, B, 0, stream>>>(esrc, rowstart, xl2, xr2, att2, bias2, out);
}

// Round 7
// 329.220 us; speedup vs baseline: 22.3853x; 1.0635x over previous
//
#include <hip/hip_runtime.h>
#include <hip/hip_bf16.h>
#include <math.h>

#define NN 50000
#define EE 800000
#define ET 850000   // EE + NN self loops
#define DIN 128
#define HEADS 8
#define DH 16
#define DOUT 16
#define NEG 0.2f
#define GM 32       // nodes per GEMM block
#define SCH 256     // scan chunk size
#define NB ((NN + SCH - 1) / SCH)   // 196 scan blocks (must be <= 256)

__device__ __forceinline__ unsigned pack2bf(float a, float b) {
    union { __hip_bfloat162 h; unsigned u; } c;
    c.h = __float22bfloat162_rn(make_float2(a, b));
    return c.u;
}
__device__ __forceinline__ float bflo(unsigned u) { return __uint_as_float(u << 16); }
__device__ __forceinline__ float bfhi(unsigned u) { return __uint_as_float(u & 0xffff0000u); }

// ---------- layer-1 GEMMs: xlb = bf16(x@Wl1), xr = x@Wr1 (register-tiled) ----------
__global__ __launch_bounds__(256) void gemm1(const float* __restrict__ x,
                                             const float* __restrict__ Wl,
                                             const float* __restrict__ Wr,
                                             unsigned short* __restrict__ xlb,
                                             float* __restrict__ xr) {
    __shared__ float xs[GM][DIN];
    int t = threadIdx.x;
    int n0 = blockIdx.x * GM;
    {   // stage 32 x-rows, coalesced float4
        int r = t >> 3, q0 = t & 7;
        int n = n0 + r;
        float4* dstq = (float4*)(xs[r]);
        if (n < NN) {
            const float4* src = (const float4*)(x + (size_t)n * DIN);
#pragma unroll
            for (int k = 0; k < 4; ++k) dstq[q0 + 8 * k] = src[q0 + 8 * k];
        } else {
#pragma unroll
            for (int k = 0; k < 4; ++k) dstq[q0 + 8 * k] = make_float4(0.f, 0.f, 0.f, 0.f);
        }
    }
    __syncthreads();
    int q = t & 63;        // 64 col-quads: 0..31 -> Wl, 32..63 -> Wr
    int g = t >> 6;        // wave-uniform node group (broadcast LDS reads)
    const float* __restrict__ W = (q < 32) ? Wl : Wr;
    int cq = q & 31;
    float4 acc[8];
#pragma unroll
    for (int j = 0; j < 8; ++j) acc[j] = make_float4(0.f, 0.f, 0.f, 0.f);
#pragma unroll 4
    for (int i = 0; i < DIN; ++i) {
        float4 w = ((const float4*)(W + (size_t)i * 128))[cq];
#pragma unroll
        for (int j = 0; j < 8; ++j) {
            float xv = xs[g * 8 + j][i];
            acc[j].x += xv * w.x; acc[j].y += xv * w.y;
            acc[j].z += xv * w.z; acc[j].w += xv * w.w;
        }
    }
    if (q < 32) {   // xl path: bf16
#pragma unroll
        for (int j = 0; j < 8; ++j) {
            int n = n0 + g * 8 + j;
            if (n < NN)
                ((uint2*)(xlb + (size_t)n * DIN))[cq] =
                    make_uint2(pack2bf(acc[j].x, acc[j].y), pack2bf(acc[j].z, acc[j].w));
        }
    } else {        // xr path: fp32
#pragma unroll
        for (int j = 0; j < 8; ++j) {
            int n = n0 + g * 8 + j;
            if (n < NN) ((float4*)(xr + (size_t)n * DIN))[cq] = acc[j];
        }
    }
}

// ---------- CSR build ----------
__global__ void deg_count(const int* __restrict__ ei, int* __restrict__ cnt) {
    int i = blockIdx.x * blockDim.x + threadIdx.x;
    if (i >= EE / 4) return;
    int4 dd = ((const int4*)(ei + EE))[i];
    atomicAdd(&cnt[dd.x], 1);
    atomicAdd(&cnt[dd.y], 1);
    atomicAdd(&cnt[dd.z], 1);
    atomicAdd(&cnt[dd.w], 1);
}

__global__ __launch_bounds__(256) void block_sums(const int* __restrict__ cnt,
                                                  int* __restrict__ bsum) {
    __shared__ int red[256];
    int b = blockIdx.x, t = threadIdx.x;
    int i = b * SCH + t;
    red[t] = (i < NN) ? cnt[i] + 1 : 0;
    __syncthreads();
#pragma unroll
    for (int off = 128; off > 0; off >>= 1) {
        if (t < off) red[t] += red[t + off];
        __syncthreads();
    }
    if (t == 0) bsum[b] = red[0];
}

__global__ __launch_bounds__(256) void scan_bsums(const int* __restrict__ bsum,
                                                  int* __restrict__ boff) {
    __shared__ int sh[256];
    int t = threadIdx.x;
    int v = (t < NB) ? bsum[t] : 0;
    sh[t] = v;
    __syncthreads();
    for (int off = 1; off < 256; off <<= 1) {
        int u = (t >= off) ? sh[t - off] : 0;
        __syncthreads();
        sh[t] += u;
        __syncthreads();
    }
    if (t < NB) boff[t] = sh[t] - v;   // exclusive block offsets
}

// writes rowstart AND the self-loop entry esrc[rowstart[i]] = i
__global__ __launch_bounds__(256) void write_rowstart(const int* __restrict__ cnt,
                                                      const int* __restrict__ boff,
                                                      int* __restrict__ rowstart,
                                                      int* __restrict__ esrc) {
    __shared__ int sh[256];
    int b = blockIdx.x, t = threadIdx.x;
    int i = b * SCH + t;
    int v = (i < NN) ? cnt[i] + 1 : 0;
    sh[t] = v;
    __syncthreads();
    for (int off = 1; off < 256; off <<= 1) {
        int u = (t >= off) ? sh[t - off] : 0;
        __syncthreads();
        sh[t] += u;
        __syncthreads();
    }
    int pos = boff[b] + sh[t] - v;
    if (i <= NN) rowstart[i] = pos;   // i==NN -> ET
    if (i < NN)  esrc[pos] = i;       // self-loop at slot 0 of each row
}

// real edges only; slot = rowstart[d] + 1 + cursor (self-loop owns slot 0)
__global__ void fill_csr(const int* __restrict__ ei, const int* __restrict__ rowstart,
                         int* __restrict__ cursor, int* __restrict__ esrc) {
    int i = blockIdx.x * blockDim.x + threadIdx.x;
    if (i >= EE / 4) return;     // EE % 4 == 0
    int4 ss = ((const int4*)ei)[i];
    int4 dd = ((const int4*)(ei + EE))[i];
    int p;
    p = atomicAdd(&cursor[dd.x], 1); esrc[rowstart[dd.x] + 1 + p] = ss.x;
    p = atomicAdd(&cursor[dd.y], 1); esrc[rowstart[dd.y] + 1 + p] = ss.y;
    p = atomicAdd(&cursor[dd.z], 1); esrc[rowstart[dd.z] + 1 + p] = ss.z;
    p = atomicAdd(&cursor[dd.w], 1); esrc[rowstart[dd.w] + 1 + p] = ss.w;
}

// ---------- layer-1 fused: logits + segment softmax + gather + bias + ELU ----------
// one wave per dst (4 dst per 256-block). Quarter-wave per edge slot: 16 lanes x
// 8 bf16 channels (one uint4/lane), 4 slots/iter. Head = q16>>1; logit reduce =
// 8 in-thread FMAs + shfl_xor(1). bf16 halves gather bytes (435->218 MB) —
// round-6 counters showed this kernel is bytes-bound (~5.9 TB/s delivered).
__global__ __launch_bounds__(256) void l1_fused(const int* __restrict__ esrc,
                                                const int* __restrict__ rowstart,
                                                const unsigned short* __restrict__ xlb,
                                                const float* __restrict__ xr,
                                                const float* __restrict__ att,
                                                const float* __restrict__ bias,
                                                float* __restrict__ hout) {
    int d = blockIdx.x * 4 + (threadIdx.x >> 6);    // NN % 4 == 0
    int lane = threadIdx.x & 63;
    int quarter = lane >> 4;
    int q16 = lane & 15;        // channel octet [8*q16, 8*q16+8)
    int rs = rowstart[d], re = rowstart[d + 1];     // re-rs >= 1 (self-loop)
    int last = re - 1;
    float4 xr0 = ((const float4*)(xr + (size_t)d * DIN))[2 * q16];
    float4 xr1 = ((const float4*)(xr + (size_t)d * DIN))[2 * q16 + 1];
    float4 at0 = ((const float4*)att)[2 * q16];
    float4 at1 = ((const float4*)att)[2 * q16 + 1];
    float4 a0 = make_float4(0.f, 0.f, 0.f, 0.f);
    float4 a1 = make_float4(0.f, 0.f, 0.f, 0.f);
    float l = 0.f;
    int slot = rs + quarter;
    int c0 = slot < last ? slot : last;
    int s0 = esrc[c0];
    int c1 = slot + 4 < last ? slot + 4 : last;
    int s1 = esrc[c1];
    uint4 row = ((const uint4*)(xlb + (size_t)s0 * DIN))[q16];
    for (; slot < re; slot += 4) {
        uint4 cur = row;
        int c2 = slot + 8 < last ? slot + 8 : last;
        int s2 = esrc[c2];                                    // 2 ahead
        row = ((const uint4*)(xlb + (size_t)s1 * DIN))[q16];  // 1 ahead
        s1 = s2;
        float f0 = bflo(cur.x), f1 = bfhi(cur.x);
        float f2 = bflo(cur.y), f3 = bfhi(cur.y);
        float f4 = bflo(cur.z), f5 = bfhi(cur.z);
        float f6 = bflo(cur.w), f7 = bfhi(cur.w);
        float v0 = f0 + xr0.x; v0 = fmaxf(v0, NEG * v0);
        float v1 = f1 + xr0.y; v1 = fmaxf(v1, NEG * v1);
        float v2 = f2 + xr0.z; v2 = fmaxf(v2, NEG * v2);
        float v3 = f3 + xr0.w; v3 = fmaxf(v3, NEG * v3);
        float v4 = f4 + xr1.x; v4 = fmaxf(v4, NEG * v4);
        float v5 = f5 + xr1.y; v5 = fmaxf(v5, NEG * v5);
        float v6 = f6 + xr1.z; v6 = fmaxf(v6, NEG * v6);
        float v7 = f7 + xr1.w; v7 = fmaxf(v7, NEG * v7);
        float w = at0.x * v0 + at0.y * v1 + at0.z * v2 + at0.w * v3
                + at1.x * v4 + at1.y * v5 + at1.z * v6 + at1.w * v7;
        w += __shfl_xor(w, 1);          // full 16-ch head logit (lane pair)
        float p = __expf(w);
        a0.x += p * f0; a0.y += p * f1; a0.z += p * f2; a0.w += p * f3;
        a1.x += p * f4; a1.y += p * f5; a1.z += p * f6; a1.w += p * f7;
        l += p;
    }
    // combine the four slot-quarters (lanes differing in bits 4,5 share channels)
#pragma unroll
    for (int off = 16; off < 64; off <<= 1) {
        a0.x += __shfl_xor(a0.x, off); a0.y += __shfl_xor(a0.y, off);
        a0.z += __shfl_xor(a0.z, off); a0.w += __shfl_xor(a0.w, off);
        a1.x += __shfl_xor(a1.x, off); a1.y += __shfl_xor(a1.y, off);
        a1.z += __shfl_xor(a1.z, off); a1.w += __shfl_xor(a1.w, off);
        l += __shfl_xor(l, off);
    }
    if (quarter == 0) {
        float inv = 1.f / l;
        float4 b0 = ((const float4*)bias)[2 * q16];
        float4 b1 = ((const float4*)bias)[2 * q16 + 1];
        float4 o0, o1;
        o0.x = a0.x * inv + b0.x; o0.x = o0.x > 0.f ? o0.x : expm1f(o0.x);
        o0.y = a0.y * inv + b0.y; o0.y = o0.y > 0.f ? o0.y : expm1f(o0.y);
        o0.z = a0.z * inv + b0.z; o0.z = o0.z > 0.f ? o0.z : expm1f(o0.z);
        o0.w = a0.w * inv + b0.w; o0.w = o0.w > 0.f ? o0.w : expm1f(o0.w);
        o1.x = a1.x * inv + b1.x; o1.x = o1.x > 0.f ? o1.x : expm1f(o1.x);
        o1.y = a1.y * inv + b1.y; o1.y = o1.y > 0.f ? o1.y : expm1f(o1.y);
        o1.z = a1.z * inv + b1.z; o1.z = o1.z > 0.f ? o1.z : expm1f(o1.z);
        o1.w = a1.w * inv + b1.w; o1.w = o1.w > 0.f ? o1.w : expm1f(o1.w);
        ((float4*)(hout + (size_t)d * DIN))[2 * q16]     = o0;
        ((float4*)(hout + (size_t)d * DIN))[2 * q16 + 1] = o1;
    }
}

// ---------- layer-2 GEMMs (register-tiled, W in L1) ----------
__global__ __launch_bounds__(256) void gemm2(const float* __restrict__ h,
                                             const float* __restrict__ Wl,
                                             const float* __restrict__ Wr,
                                             float* __restrict__ xl, float* __restrict__ xr) {
    __shared__ float xs[GM][DIN + 4];
    int t = threadIdx.x;
    int n0 = blockIdx.x * GM;
    {
        int r = t >> 3, q0 = t & 7;
        int n = n0 + r;
        float4* dstq = (float4*)(xs[r]);
        if (n < NN) {
            const float4* src = (const float4*)(h + (size_t)n * DIN);
#pragma unroll
            for (int k = 0; k < 4; ++k) dstq[q0 + 8 * k] = src[q0 + 8 * k];
        } else {
#pragma unroll
            for (int k = 0; k < 4; ++k) dstq[q0 + 8 * k] = make_float4(0.f, 0.f, 0.f, 0.f);
        }
    }
    __syncthreads();
    int q = t & 7;          // 8 col-quads: 0..3 -> Wl2, 4..7 -> Wr2
    int g = t >> 3;         // node within tile
    const float* __restrict__ W = (q < 4) ? Wl : Wr;
    int cq = q & 3;
    float4 acc = make_float4(0.f, 0.f, 0.f, 0.f);
#pragma unroll 8
    for (int i = 0; i < DIN; ++i) {
        float4 w = ((const float4*)(W + (size_t)i * DOUT))[cq];
        float xv = xs[g][i];
        acc.x += xv * w.x; acc.y += xv * w.y; acc.z += xv * w.z; acc.w += xv * w.w;
    }
    int n = n0 + g;
    if (n < NN) {
        float* __restrict__ dst = (q < 4) ? xl : xr;
        ((float4*)(dst + (size_t)n * DOUT))[cq] = acc;
    }
}

// ---------- layer-2 fused: softmax + gather + bias + log_softmax ----------
__global__ __launch_bounds__(256) void l2_fused(const int* __restrict__ esrc,
                                                const int* __restrict__ rowstart,
                                                const float* __restrict__ xl,
                                                const float* __restrict__ xr,
                                                const float* __restrict__ att,
                                                const float* __restrict__ bias,
                                                float* __restrict__ out) {
    int d = blockIdx.x * 4 + (threadIdx.x >> 6);    // NN % 4 == 0
    int lane = threadIdx.x & 63;
    int sl = lane >> 2;     // edge slot group 0..15
    int q = lane & 3;       // channel quad
    int rs = rowstart[d], re = rowstart[d + 1];
    int last = re - 1;
    float4 xrq = ((const float4*)(xr + (size_t)d * DOUT))[q];
    float4 atq = ((const float4*)att)[q];
    float4 acc = make_float4(0.f, 0.f, 0.f, 0.f);
    float l = 0.f;
    int slot = rs + sl;
    int c0 = slot < last ? slot : last;
    int s0 = esrc[c0];
    for (; slot < re; slot += 16) {
        int c1 = slot + 16 < last ? slot + 16 : last;
        int s1 = esrc[c1];
        float4 cur = ((const float4*)(xl + (size_t)s0 * DOUT))[q];
        s0 = s1;
        float v0 = cur.x + xrq.x; v0 = fmaxf(v0, NEG * v0);
        float v1 = cur.y + xrq.y; v1 = fmaxf(v1, NEG * v1);
        float v2 = cur.z + xrq.z; v2 = fmaxf(v2, NEG * v2);
        float v3 = cur.w + xrq.w; v3 = fmaxf(v3, NEG * v3);
        float w = atq.x * v0 + atq.y * v1 + atq.z * v2 + atq.w * v3;
        w += __shfl_xor(w, 1);
        w += __shfl_xor(w, 2);          // full 16-ch logit
        float p = __expf(w);
        acc.x += p * cur.x; acc.y += p * cur.y;
        acc.z += p * cur.z; acc.w += p * cur.w;
        l += p;
    }
    // reduce across the 16 slot groups
#pragma unroll
    for (int off = 4; off < 64; off <<= 1) {
        acc.x += __shfl_xor(acc.x, off);
        acc.y += __shfl_xor(acc.y, off);
        acc.z += __shfl_xor(acc.z, off);
        acc.w += __shfl_xor(acc.w, off);
        l += __shfl_xor(l, off);
    }
    float inv = 1.f / l;
    float4 b = ((const float4*)bias)[q];
    float4 v;
    v.x = acc.x * inv + b.x; v.y = acc.y * inv + b.y;
    v.z = acc.z * inv + b.z; v.w = acc.w * inv + b.w;
    // log_softmax over the 16 channels (4 in-thread + 4-lane shfl)
    float m = fmaxf(fmaxf(v.x, v.y), fmaxf(v.z, v.w));
    m = fmaxf(m, __shfl_xor(m, 1));
    m = fmaxf(m, __shfl_xor(m, 2));
    float es = __expf(v.x - m) + __expf(v.y - m) + __expf(v.z - m) + __expf(v.w - m);
    es += __shfl_xor(es, 1);
    es += __shfl_xor(es, 2);
    float lse = m + __logf(es);
    if (sl == 0) {
        ((float4*)(out + (size_t)d * DOUT))[q] = v;
        float4 ls;
        ls.x = v.x - lse; ls.y = v.y - lse; ls.z = v.z - lse; ls.w = v.w - lse;
        ((float4*)(out + (size_t)NN * DOUT + (size_t)d * DOUT))[q] = ls;
    }
}

extern "C" void kernel_launch(void* const* d_in, const int* in_sizes, int n_in,
                              void* d_out, int out_size, void* d_ws, size_t ws_size,
                              hipStream_t stream) {
    const float* x     = (const float*)d_in[0];
    const int*   ei    = (const int*)d_in[1];
    const float* Wl1   = (const float*)d_in[2];
    const float* Wr1   = (const float*)d_in[3];
    const float* att1  = (const float*)d_in[4];
    const float* bias1 = (const float*)d_in[5];
    const float* Wl2   = (const float*)d_in[6];
    const float* Wr2   = (const float*)d_in[7];
    const float* att2  = (const float*)d_in[8];
    const float* bias2 = (const float*)d_in[9];
    float* out = (float*)d_out;

    // ---- workspace layout ----
    float* xr1    = (float*)d_ws;                    // NN*128 fp32
    float* hout   = xr1 + (size_t)NN * DIN;          // NN*128 fp32
    float* xl2    = hout + (size_t)NN * DIN;         // NN*16
    float* xr2    = xl2 + (size_t)NN * DOUT;         // NN*16
    unsigned short* xlb = (unsigned short*)(xr2 + (size_t)NN * DOUT); // NN*128 bf16
    int*   esrc   = (int*)(xlb + (size_t)NN * DIN);  // ET
    int*   rowstart = esrc + (size_t)ET;             // NN+1
    int*   bsum   = rowstart + NN + 1;               // NB
    int*   boff   = bsum + NB;                       // NB
    // zero-init region:
    int*   cnt    = boff + NB;                       // NN
    int*   cursor = cnt + NN;                        // NN

    hipMemsetAsync(cnt, 0, (size_t)2 * NN * sizeof(int), stream);

    const int B = 256;
    int gN = (NN + GM - 1) / GM;
    gemm1<<<gN, B, 0, stream>>>(x, Wl1, Wr1, xlb, xr1);

    deg_count<<<(EE / 4 + B - 1) / B, B, 0, stream>>>(ei, cnt);
    block_sums<<<NB, B, 0, stream>>>(cnt, bsum);
    scan_bsums<<<1, B, 0, stream>>>(bsum, boff);
    write_rowstart<<<NB, B, 0, stream>>>(cnt, boff, rowstart, esrc);
    fill_csr<<<(EE / 4 + B - 1) / B, B, 0, stream>>>(ei, rowstart, cursor, esrc);

    l1_fused<<<NN / 4, B, 0, stream>>>(esrc, rowstart, xlb, xr1, att1, bias1, hout);

    gemm2<<<gN, B, 0, stream>>>(hout, Wl2, Wr2, xl2, xr2);

    l2_fused<<<NN / 4, B, 0, stream>>>(esrc, rowstart, xl2, xr2, att2, bias2, out);
}

// Round 9
// 300.793 us; speedup vs baseline: 24.5009x; 1.0945x over previous
//
#include <hip/hip_runtime.h>
#include <hip/hip_bf16.h>
#include <math.h>

#define NN 50000
#define EE 800000
#define ET 850000   // EE + NN self loops
#define DIN 128
#define HEADS 8
#define DH 16
#define DOUT 16
#define NEG 0.2f
#define GM 32       // nodes per GEMM block
#define SCH 256     // scan chunk size
#define NB ((NN + SCH - 1) / SCH)   // 196 scan blocks (must be <= 256)

typedef __attribute__((ext_vector_type(8))) short bf16x8;
typedef __attribute__((ext_vector_type(4))) float f32x4;

__device__ __forceinline__ unsigned pack2bf(float a, float b) {
    union { __hip_bfloat162 h; unsigned u; } c;
    c.h = __float22bfloat162_rn(make_float2(a, b));
    return c.u;
}
__device__ __forceinline__ unsigned short f2bf(float v) {
    union { __hip_bfloat16 h; unsigned short u; } c;
    c.h = __float2bfloat16(v);
    return c.u;
}
__device__ __forceinline__ float bflo(unsigned u) { return __uint_as_float(u << 16); }
__device__ __forceinline__ float bfhi(unsigned u) { return __uint_as_float(u & 0xffff0000u); }

// ---------- W convert+transpose: Wb[n][k] = bf16(W[k][n]), n in [0,256) ----------
__global__ __launch_bounds__(256) void wcvt(const float* __restrict__ Wl,
                                            const float* __restrict__ Wr,
                                            unsigned short* __restrict__ Wb) {
    int i = blockIdx.x * 256 + threadIdx.x;   // 32768 threads
    int n = i >> 7, k = i & 127;
    float v = (n < 128) ? Wl[k * 128 + n] : Wr[k * 128 + (n - 128)];
    Wb[i] = f2bf(v);
}

// ---------- layer-1 GEMM via MFMA: [xlb | xr] = x @ [Wl | Wr] ----------
// block: 32 nodes x 256 cols, 4 waves (64 cols each). K=128 in 4 steps of 32.
// A (x, bf16) staged in LDS rows padded to 136; B from Wb (L1-hot 16B loads).
// Layouts per m89-verified 16x16x32: A[m=lane&15][k=quad*8+j],
// B[k=quad*8+j][n=lane&15], D col=lane&15 row=quad*4+reg.
__global__ __launch_bounds__(256) void gemm1(const float* __restrict__ x,
                                             const unsigned short* __restrict__ Wb,
                                             unsigned short* __restrict__ xlb,
                                             float* __restrict__ xr) {
    __shared__ unsigned short As[GM][136];   // pad 128->136 (2-way LDS aliasing = free)
    int t = threadIdx.x;
    int n0 = blockIdx.x * GM;
    {   // stage: 32 rows x 128 ch fp32 -> bf16 LDS; thread = (row, 16-ch segment)
        int row = t >> 3, seg = t & 7;
        int nsrc = n0 + row < NN ? n0 + row : NN - 1;   // clamp: safe read, store guarded
        const float4* xp = (const float4*)(x + (size_t)nsrc * DIN + 16 * seg);
        float4 v0 = xp[0], v1 = xp[1], v2 = xp[2], v3 = xp[3];
        uint4 p0 = make_uint4(pack2bf(v0.x, v0.y), pack2bf(v0.z, v0.w),
                              pack2bf(v1.x, v1.y), pack2bf(v1.z, v1.w));
        uint4 p1 = make_uint4(pack2bf(v2.x, v2.y), pack2bf(v2.z, v2.w),
                              pack2bf(v3.x, v3.y), pack2bf(v3.z, v3.w));
        *(uint4*)&As[row][16 * seg]     = p0;
        *(uint4*)&As[row][16 * seg + 8] = p1;
    }
    __syncthreads();
    int lane = t & 63, w = t >> 6;
    int m = lane & 15, quad = lane >> 4;
    f32x4 acc[2][4];
#pragma unroll
    for (int mt = 0; mt < 2; ++mt)
#pragma unroll
        for (int nt = 0; nt < 4; ++nt) acc[mt][nt] = (f32x4){0.f, 0.f, 0.f, 0.f};
#pragma unroll
    for (int ks = 0; ks < 4; ++ks) {
        int k = 32 * ks + 8 * quad;
        bf16x8 a0 = *(const bf16x8*)&As[m][k];
        bf16x8 a1 = *(const bf16x8*)&As[16 + m][k];
#pragma unroll
        for (int nt = 0; nt < 4; ++nt) {
            int n = 64 * w + 16 * nt + m;
            bf16x8 b = *(const bf16x8*)(Wb + (size_t)n * 128 + k);
            acc[0][nt] = __builtin_amdgcn_mfma_f32_16x16x32_bf16(a0, b, acc[0][nt], 0, 0, 0);
            acc[1][nt] = __builtin_amdgcn_mfma_f32_16x16x32_bf16(a1, b, acc[1][nt], 0, 0, 0);
        }
    }
    // store: D[row=quad*4+r][col=lane&15] per tile; col<128 -> xlb bf16, else xr fp32
#pragma unroll
    for (int mt = 0; mt < 2; ++mt) {
#pragma unroll
        for (int nt = 0; nt < 4; ++nt) {
            int col = 64 * w + 16 * nt + m;       // wave-uniform half selection
            int rbase = n0 + 16 * mt + 4 * quad;
            if (col < 128) {
#pragma unroll
                for (int r = 0; r < 4; ++r) {
                    int row = rbase + r;
                    if (row < NN) xlb[(size_t)row * DIN + col] = f2bf(acc[mt][nt][r]);
                }
            } else {
#pragma unroll
                for (int r = 0; r < 4; ++r) {
                    int row = rbase + r;
                    if (row < NN) xr[(size_t)row * DIN + (col - 128)] = acc[mt][nt][r];
                }
            }
        }
    }
}

// ---------- CSR build ----------
__global__ void deg_count(const int* __restrict__ ei, int* __restrict__ cnt) {
    int i = blockIdx.x * blockDim.x + threadIdx.x;
    if (i >= EE / 4) return;
    int4 dd = ((const int4*)(ei + EE))[i];
    atomicAdd(&cnt[dd.x], 1);
    atomicAdd(&cnt[dd.y], 1);
    atomicAdd(&cnt[dd.z], 1);
    atomicAdd(&cnt[dd.w], 1);
}

__global__ __launch_bounds__(256) void block_sums(const int* __restrict__ cnt,
                                                  int* __restrict__ bsum) {
    __shared__ int red[256];
    int b = blockIdx.x, t = threadIdx.x;
    int i = b * SCH + t;
    red[t] = (i < NN) ? cnt[i] + 1 : 0;
    __syncthreads();
#pragma unroll
    for (int off = 128; off > 0; off >>= 1) {
        if (t < off) red[t] += red[t + off];
        __syncthreads();
    }
    if (t == 0) bsum[b] = red[0];
}

__global__ __launch_bounds__(256) void scan_bsums(const int* __restrict__ bsum,
                                                  int* __restrict__ boff) {
    __shared__ int sh[256];
    int t = threadIdx.x;
    int v = (t < NB) ? bsum[t] : 0;
    sh[t] = v;
    __syncthreads();
    for (int off = 1; off < 256; off <<= 1) {
        int u = (t >= off) ? sh[t - off] : 0;
        __syncthreads();
        sh[t] += u;
        __syncthreads();
    }
    if (t < NB) boff[t] = sh[t] - v;   // exclusive block offsets
}

// writes rowstart AND the self-loop entry esrc[rowstart[i]] = i
__global__ __launch_bounds__(256) void write_rowstart(const int* __restrict__ cnt,
                                                      const int* __restrict__ boff,
                                                      int* __restrict__ rowstart,
                                                      int* __restrict__ esrc) {
    __shared__ int sh[256];
    int b = blockIdx.x, t = threadIdx.x;
    int i = b * SCH + t;
    int v = (i < NN) ? cnt[i] + 1 : 0;
    sh[t] = v;
    __syncthreads();
    for (int off = 1; off < 256; off <<= 1) {
        int u = (t >= off) ? sh[t - off] : 0;
        __syncthreads();
        sh[t] += u;
        __syncthreads();
    }
    int pos = boff[b] + sh[t] - v;
    if (i <= NN) rowstart[i] = pos;   // i==NN -> ET
    if (i < NN)  esrc[pos] = i;       // self-loop at slot 0 of each row
}

// real edges only; slot = rowstart[d] + 1 + cursor (self-loop owns slot 0)
__global__ void fill_csr(const int* __restrict__ ei, const int* __restrict__ rowstart,
                         int* __restrict__ cursor, int* __restrict__ esrc) {
    int i = blockIdx.x * blockDim.x + threadIdx.x;
    if (i >= EE / 4) return;     // EE % 4 == 0
    int4 ss = ((const int4*)ei)[i];
    int4 dd = ((const int4*)(ei + EE))[i];
    int p;
    p = atomicAdd(&cursor[dd.x], 1); esrc[rowstart[dd.x] + 1 + p] = ss.x;
    p = atomicAdd(&cursor[dd.y], 1); esrc[rowstart[dd.y] + 1 + p] = ss.y;
    p = atomicAdd(&cursor[dd.z], 1); esrc[rowstart[dd.z] + 1 + p] = ss.z;
    p = atomicAdd(&cursor[dd.w], 1); esrc[rowstart[dd.w] + 1 + p] = ss.w;
}

// ---------- layer-1 fused: logits + segment softmax + gather + bias + ELU ----------
// one wave per dst; quarter-wave per edge slot: 16 lanes x 8 bf16 channels.
__global__ __launch_bounds__(256) void l1_fused(const int* __restrict__ esrc,
                                                const int* __restrict__ rowstart,
                                                const unsigned short* __restrict__ xlb,
                                                const float* __restrict__ xr,
                                                const float* __restrict__ att,
                                                const float* __restrict__ bias,
                                                float* __restrict__ hout) {
    int d = blockIdx.x * 4 + (threadIdx.x >> 6);    // NN % 4 == 0
    int lane = threadIdx.x & 63;
    int quarter = lane >> 4;
    int q16 = lane & 15;        // channel octet [8*q16, 8*q16+8)
    int rs = rowstart[d], re = rowstart[d + 1];     // re-rs >= 1 (self-loop)
    int last = re - 1;
    float4 xr0 = ((const float4*)(xr + (size_t)d * DIN))[2 * q16];
    float4 xr1 = ((const float4*)(xr + (size_t)d * DIN))[2 * q16 + 1];
    float4 at0 = ((const float4*)att)[2 * q16];
    float4 at1 = ((const float4*)att)[2 * q16 + 1];
    float4 a0 = make_float4(0.f, 0.f, 0.f, 0.f);
    float4 a1 = make_float4(0.f, 0.f, 0.f, 0.f);
    float l = 0.f;
    int slot = rs + quarter;
    int c0 = slot < last ? slot : last;
    int s0 = esrc[c0];
    int c1 = slot + 4 < last ? slot + 4 : last;
    int s1 = esrc[c1];
    uint4 row = ((const uint4*)(xlb + (size_t)s0 * DIN))[q16];
    for (; slot < re; slot += 4) {
        uint4 cur = row;
        int c2 = slot + 8 < last ? slot + 8 : last;
        int s2 = esrc[c2];                                    // 2 ahead
        row = ((const uint4*)(xlb + (size_t)s1 * DIN))[q16];  // 1 ahead
        s1 = s2;
        float f0 = bflo(cur.x), f1 = bfhi(cur.x);
        float f2 = bflo(cur.y), f3 = bfhi(cur.y);
        float f4 = bflo(cur.z), f5 = bfhi(cur.z);
        float f6 = bflo(cur.w), f7 = bfhi(cur.w);
        float v0 = f0 + xr0.x; v0 = fmaxf(v0, NEG * v0);
        float v1 = f1 + xr0.y; v1 = fmaxf(v1, NEG * v1);
        float v2 = f2 + xr0.z; v2 = fmaxf(v2, NEG * v2);
        float v3 = f3 + xr0.w; v3 = fmaxf(v3, NEG * v3);
        float v4 = f4 + xr1.x; v4 = fmaxf(v4, NEG * v4);
        float v5 = f5 + xr1.y; v5 = fmaxf(v5, NEG * v5);
        float v6 = f6 + xr1.z; v6 = fmaxf(v6, NEG * v6);
        float v7 = f7 + xr1.w; v7 = fmaxf(v7, NEG * v7);
        float w = at0.x * v0 + at0.y * v1 + at0.z * v2 + at0.w * v3
                + at1.x * v4 + at1.y * v5 + at1.z * v6 + at1.w * v7;
        w += __shfl_xor(w, 1);          // full 16-ch head logit (lane pair)
        float p = __expf(w);
        a0.x += p * f0; a0.y += p * f1; a0.z += p * f2; a0.w += p * f3;
        a1.x += p * f4; a1.y += p * f5; a1.z += p * f6; a1.w += p * f7;
        l += p;
    }
#pragma unroll
    for (int off = 16; off < 64; off <<= 1) {
        a0.x += __shfl_xor(a0.x, off); a0.y += __shfl_xor(a0.y, off);
        a0.z += __shfl_xor(a0.z, off); a0.w += __shfl_xor(a0.w, off);
        a1.x += __shfl_xor(a1.x, off); a1.y += __shfl_xor(a1.y, off);
        a1.z += __shfl_xor(a1.z, off); a1.w += __shfl_xor(a1.w, off);
        l += __shfl_xor(l, off);
    }
    if (quarter == 0) {
        float inv = 1.f / l;
        float4 b0 = ((const float4*)bias)[2 * q16];
        float4 b1 = ((const float4*)bias)[2 * q16 + 1];
        float4 o0, o1;
        o0.x = a0.x * inv + b0.x; o0.x = o0.x > 0.f ? o0.x : expm1f(o0.x);
        o0.y = a0.y * inv + b0.y; o0.y = o0.y > 0.f ? o0.y : expm1f(o0.y);
        o0.z = a0.z * inv + b0.z; o0.z = o0.z > 0.f ? o0.z : expm1f(o0.z);
        o0.w = a0.w * inv + b0.w; o0.w = o0.w > 0.f ? o0.w : expm1f(o0.w);
        o1.x = a1.x * inv + b1.x; o1.x = o1.x > 0.f ? o1.x : expm1f(o1.x);
        o1.y = a1.y * inv + b1.y; o1.y = o1.y > 0.f ? o1.y : expm1f(o1.y);
        o1.z = a1.z * inv + b1.z; o1.z = o1.z > 0.f ? o1.z : expm1f(o1.z);
        o1.w = a1.w * inv + b1.w; o1.w = o1.w > 0.f ? o1.w : expm1f(o1.w);
        ((float4*)(hout + (size_t)d * DIN))[2 * q16]     = o0;
        ((float4*)(hout + (size_t)d * DIN))[2 * q16 + 1] = o1;
    }
}

// ---------- layer-2 GEMMs (register-tiled, W in L1) ----------
__global__ __launch_bounds__(256) void gemm2(const float* __restrict__ h,
                                             const float* __restrict__ Wl,
                                             const float* __restrict__ Wr,
                                             float* __restrict__ xl, float* __restrict__ xr) {
    __shared__ float xs[GM][DIN + 4];
    int t = threadIdx.x;
    int n0 = blockIdx.x * GM;
    {
        int r = t >> 3, q0 = t & 7;
        int n = n0 + r;
        float4* dstq = (float4*)(xs[r]);
        if (n < NN) {
            const float4* src = (const float4*)(h + (size_t)n * DIN);
#pragma unroll
            for (int k = 0; k < 4; ++k) dstq[q0 + 8 * k] = src[q0 + 8 * k];
        } else {
#pragma unroll
            for (int k = 0; k < 4; ++k) dstq[q0 + 8 * k] = make_float4(0.f, 0.f, 0.f, 0.f);
        }
    }
    __syncthreads();
    int q = t & 7;          // 8 col-quads: 0..3 -> Wl2, 4..7 -> Wr2
    int g = t >> 3;         // node within tile
    const float* __restrict__ W = (q < 4) ? Wl : Wr;
    int cq = q & 3;
    float4 acc = make_float4(0.f, 0.f, 0.f, 0.f);
#pragma unroll 8
    for (int i = 0; i < DIN; ++i) {
        float4 w = ((const float4*)(W + (size_t)i * DOUT))[cq];
        float xv = xs[g][i];
        acc.x += xv * w.x; acc.y += xv * w.y; acc.z += xv * w.z; acc.w += xv * w.w;
    }
    int n = n0 + g;
    if (n < NN) {
        float* __restrict__ dst = (q < 4) ? xl : xr;
        ((float4*)(dst + (size_t)n * DOUT))[cq] = acc;
    }
}

// ---------- layer-2 fused: softmax + gather + bias + log_softmax ----------
__global__ __launch_bounds__(256) void l2_fused(const int* __restrict__ esrc,
                                                const int* __restrict__ rowstart,
                                                const float* __restrict__ xl,
                                                const float* __restrict__ xr,
                                                const float* __restrict__ att,
                                                const float* __restrict__ bias,
                                                float* __restrict__ out) {
    int d = blockIdx.x * 4 + (threadIdx.x >> 6);    // NN % 4 == 0
    int lane = threadIdx.x & 63;
    int sl = lane >> 2;     // edge slot group 0..15
    int q = lane & 3;       // channel quad
    int rs = rowstart[d], re = rowstart[d + 1];
    int last = re - 1;
    float4 xrq = ((const float4*)(xr + (size_t)d * DOUT))[q];
    float4 atq = ((const float4*)att)[q];
    float4 acc = make_float4(0.f, 0.f, 0.f, 0.f);
    float l = 0.f;
    int slot = rs + sl;
    int c0 = slot < last ? slot : last;
    int s0 = esrc[c0];
    for (; slot < re; slot += 16) {
        int c1 = slot + 16 < last ? slot + 16 : last;
        int s1 = esrc[c1];
        float4 cur = ((const float4*)(xl + (size_t)s0 * DOUT))[q];
        s0 = s1;
        float v0 = cur.x + xrq.x; v0 = fmaxf(v0, NEG * v0);
        float v1 = cur.y + xrq.y; v1 = fmaxf(v1, NEG * v1);
        float v2 = cur.z + xrq.z; v2 = fmaxf(v2, NEG * v2);
        float v3 = cur.w + xrq.w; v3 = fmaxf(v3, NEG * v3);
        float w = atq.x * v0 + atq.y * v1 + atq.z * v2 + atq.w * v3;
        w += __shfl_xor(w, 1);
        w += __shfl_xor(w, 2);          // full 16-ch logit
        float p = __expf(w);
        acc.x += p * cur.x; acc.y += p * cur.y;
        acc.z += p * cur.z; acc.w += p * cur.w;
        l += p;
    }
#pragma unroll
    for (int off = 4; off < 64; off <<= 1) {
        acc.x += __shfl_xor(acc.x, off);
        acc.y += __shfl_xor(acc.y, off);
        acc.z += __shfl_xor(acc.z, off);
        acc.w += __shfl_xor(acc.w, off);
        l += __shfl_xor(l, off);
    }
    float inv = 1.f / l;
    float4 b = ((const float4*)bias)[q];
    float4 v;
    v.x = acc.x * inv + b.x; v.y = acc.y * inv + b.y;
    v.z = acc.z * inv + b.z; v.w = acc.w * inv + b.w;
    float m = fmaxf(fmaxf(v.x, v.y), fmaxf(v.z, v.w));
    m = fmaxf(m, __shfl_xor(m, 1));
    m = fmaxf(m, __shfl_xor(m, 2));
    float es = __expf(v.x - m) + __expf(v.y - m) + __expf(v.z - m) + __expf(v.w - m);
    es += __shfl_xor(es, 1);
    es += __shfl_xor(es, 2);
    float lse = m + __logf(es);
    if (sl == 0) {
        ((float4*)(out + (size_t)d * DOUT))[q] = v;
        float4 ls;
        ls.x = v.x - lse; ls.y = v.y - lse; ls.z = v.z - lse; ls.w = v.w - lse;
        ((float4*)(out + (size_t)NN * DOUT + (size_t)d * DOUT))[q] = ls;
    }
}

extern "C" void kernel_launch(void* const* d_in, const int* in_sizes, int n_in,
                              void* d_out, int out_size, void* d_ws, size_t ws_size,
                              hipStream_t stream) {
    const float* x     = (const float*)d_in[0];
    const int*   ei    = (const int*)d_in[1];
    const float* Wl1   = (const float*)d_in[2];
    const float* Wr1   = (const float*)d_in[3];
    const float* att1  = (const float*)d_in[4];
    const float* bias1 = (const float*)d_in[5];
    const float* Wl2   = (const float*)d_in[6];
    const float* Wr2   = (const float*)d_in[7];
    const float* att2  = (const float*)d_in[8];
    const float* bias2 = (const float*)d_in[9];
    float* out = (float*)d_out;

    // ---- workspace layout ----
    float* xr1    = (float*)d_ws;                    // NN*128 fp32
    float* hout   = xr1 + (size_t)NN * DIN;          // NN*128 fp32
    float* xl2    = hout + (size_t)NN * DIN;         // NN*16
    float* xr2    = xl2 + (size_t)NN * DOUT;         // NN*16
    unsigned short* xlb = (unsigned short*)(xr2 + (size_t)NN * DOUT); // NN*128 bf16
    unsigned short* Wb  = xlb + (size_t)NN * DIN;    // 256*128 bf16
    int*   esrc   = (int*)(Wb + 256 * 128);          // ET
    int*   rowstart = esrc + (size_t)ET;             // NN+1
    int*   bsum   = rowstart + NN + 1;               // NB
    int*   boff   = bsum + NB;                       // NB
    // zero-init region:
    int*   cnt    = boff + NB;                       // NN
    int*   cursor = cnt + NN;                        // NN

    hipMemsetAsync(cnt, 0, (size_t)2 * NN * sizeof(int), stream);

    const int B = 256;
    wcvt<<<128, B, 0, stream>>>(Wl1, Wr1, Wb);
    gemm1<<<(NN + GM - 1) / GM, B, 0, stream>>>(x, Wb, xlb, xr1);

    deg_count<<<(EE / 4 + B - 1) / B, B, 0, stream>>>(ei, cnt);
    block_sums<<<NB, B, 0, stream>>>(cnt, bsum);
    scan_bsums<<<1, B, 0, stream>>>(bsum, boff);
    write_rowstart<<<NB, B, 0, stream>>>(cnt, boff, rowstart, esrc);
    fill_csr<<<(EE / 4 + B - 1) / B, B, 0, stream>>>(ei, rowstart, cursor, esrc);

    l1_fused<<<NN / 4, B, 0, stream>>>(esrc, rowstart, xlb, xr1, att1, bias1, hout);

    gemm2<<<(NN + GM - 1) / GM, B, 0, stream>>>(hout, Wl2, Wr2, xl2, xr2);

    l2_fused<<<NN / 4, B, 0, stream>>>(esrc, rowstart, xl2, xr2, att2, bias2, out);
}